// Round 2
// baseline (3994.522 us; speedup 1.0000x reference)
//
#include <hip/hip_runtime.h>
#include <math.h>

#define NU_N 200000
#define NS_N 50000
#define E_N  1000000
#define M_N  100000

// ---- workspace layout (bytes), total ~257 MB ----
static constexpr size_t OFF_AGGU = 0;            // NU x 128 f32 = 102,400,000
static constexpr size_t OFF_AGGS = 102400000;    // NS x 128 f32 =  25,600,000
static constexpr size_t OFF_CNTU = 128000000;    // NU f32 = 800,000
static constexpr size_t OFF_CNTS = 128800000;    // NS f32 = 200,000
static constexpr size_t OFF_U    = 129000000;    // NU x 128 f32 (u1, then u2 in-place)
static constexpr size_t OFF_S    = 231400000;    // NS x 128 f32 (s1, then s2 in-place)
static constexpr size_t OFF_AGEW = 257000000;    // 9 x 128 f32
static constexpr size_t OFF_GENW = 257004608;    // 3 x 128 f32

// tiny: ageW = age_emb @ W1ur[0:32,:], genW = gen_emb @ W1ur[32:64,:]
__global__ void build_tables_k(const float* __restrict__ age, const float* __restrict__ gen,
                               const float* __restrict__ W1ur, float* __restrict__ ageW,
                               float* __restrict__ genW) {
  int j = threadIdx.x;  // 0..127
  for (int a = 0; a < 9; ++a) {
    float acc = 0.f;
    for (int k = 0; k < 32; ++k) acc += age[a * 32 + k] * W1ur[k * 128 + j];
    ageW[a * 128 + j] = acc;
  }
  for (int g = 0; g < 3; ++g) {
    float acc = 0.f;
    for (int k = 0; k < 32; ++k) acc += gen[g * 32 + k] * W1ur[(32 + k) * 128 + j];
    genW[g * 128 + j] = acc;
  }
}

// Layer-1 edge scatter: one wave per edge (grid-stride).
__global__ void scatter1_k(const int* __restrict__ su, const int* __restrict__ ds,
                           const int* __restrict__ ss, const int* __restrict__ du,
                           const float* __restrict__ xs, const float* __restrict__ xu,
                           const int* __restrict__ x1,
                           const float* __restrict__ age, const float* __restrict__ gen,
                           float* __restrict__ aggU, float* __restrict__ aggS,
                           float* __restrict__ cntU, float* __restrict__ cntS) {
  int wid  = (blockIdx.x * blockDim.x + threadIdx.x) >> 6;
  int lane = threadIdx.x & 63;
  int nw   = (gridDim.x * blockDim.x) >> 6;
  for (int e = wid; e < E_N; e += nw) {
    int eu = su[e];  // user source  (user -> seller edge)
    int es = ds[e];  // seller dst
    int fs = ss[e];  // seller source (seller -> user edge)
    int fu = du[e];  // user dst
    // user-update aggregation: sum of seller features (64 dims)
    atomicAdd(&aggU[(size_t)fu * 64 + lane], xs[(size_t)fs * 64 + lane]);
    // seller-update aggregation: sum of x_u (128 dims; first 64 = age||gen emb)
    int a = x1[2 * eu], g = x1[2 * eu + 1];
    float v0 = (lane < 32) ? age[a * 32 + lane] : gen[g * 32 + (lane - 32)];
    float v1 = xu[(size_t)eu * 64 + lane];
    atomicAdd(&aggS[(size_t)es * 128 + lane], v0);
    atomicAdd(&aggS[(size_t)es * 128 + 64 + lane], v1);
    if (lane == 0) {
      atomicAdd(&cntU[fu], 1.0f);
      atomicAdd(&cntS[es], 1.0f);
    }
  }
}

// Layer-2 edge scatter: aggU[du] += s1[ss] (128); aggS[ds] += u1[su] (128)
__global__ void scatter2_k(const int* __restrict__ su, const int* __restrict__ ds,
                           const int* __restrict__ ss, const int* __restrict__ du,
                           const float* __restrict__ u1, const float* __restrict__ s1,
                           float* __restrict__ aggU, float* __restrict__ aggS) {
  int wid  = (blockIdx.x * blockDim.x + threadIdx.x) >> 6;
  int lane = threadIdx.x & 63;
  int nw   = (gridDim.x * blockDim.x) >> 6;
  for (int e = wid; e < E_N; e += nw) {
    int eu = su[e], es = ds[e], fs = ss[e], fu = du[e];
    atomicAdd(&aggU[(size_t)fu * 128 + lane],      s1[(size_t)fs * 128 + lane]);
    atomicAdd(&aggU[(size_t)fu * 128 + 64 + lane], s1[(size_t)fs * 128 + 64 + lane]);
    atomicAdd(&aggS[(size_t)es * 128 + lane],      u1[(size_t)eu * 128 + lane]);
    atomicAdd(&aggS[(size_t)es * 128 + 64 + lane], u1[(size_t)eu * 128 + 64 + lane]);
  }
}

// Per-row dense update: out[i,:] = relu(bias + mean_i @ Wl + self_i @ Wr[wrOff:,:] (+ tables))
// block = 128 threads, thread j owns output column j; rows grid-strided over blocks.
// NOTE: self/out may alias (in-place layer 2) — each block reads row i into LDS
// before writing row i, so this is safe; no __restrict__ on those two.
__global__ void rowgemm_k(int nrows,
                          const float* __restrict__ mean, const float* __restrict__ cnt, int meanDim,
                          const float* __restrict__ Wl,
                          const float* self, int selfDim,
                          const float* __restrict__ Wr, int wrOff,
                          const float* __restrict__ bias,
                          const float* __restrict__ tblA, const float* __restrict__ tblG,
                          const int* __restrict__ x1,
                          float* out) {
  __shared__ float smM[128];
  __shared__ float smS[128];
  int j = threadIdx.x;
  for (int i = blockIdx.x; i < nrows; i += gridDim.x) {
    if (j < meanDim) {
      float inv = 1.0f / fmaxf(cnt[i], 1.0f);
      smM[j] = mean[(size_t)i * meanDim + j] * inv;
    }
    if (j < selfDim) smS[j] = self[(size_t)i * selfDim + j];
    __syncthreads();
    float acc = bias[j];
    if (tblA) acc += tblA[x1[2 * i] * 128 + j] + tblG[x1[2 * i + 1] * 128 + j];
#pragma unroll 8
    for (int k = 0; k < meanDim; ++k) acc += smM[k] * Wl[k * 128 + j];
#pragma unroll 8
    for (int k = 0; k < selfDim; ++k) acc += smS[k] * Wr[(wrOff + k) * 128 + j];
    acc = fmaxf(acc, 0.0f);
    out[(size_t)i * 128 + j] = acc;
    __syncthreads();
  }
}

// Final: out[m] = sigmoid(u2[mu[m]] . lw[0:128] + s2[ms[m]] . lw[128:256] + lb)
__global__ void final_k(const float* __restrict__ u2, const float* __restrict__ s2,
                        const int* __restrict__ mu, const int* __restrict__ ms,
                        const float* __restrict__ lw, const float* __restrict__ lb,
                        float* __restrict__ out) {
  int wid  = (blockIdx.x * blockDim.x + threadIdx.x) >> 6;
  int lane = threadIdx.x & 63;
  int nw   = (gridDim.x * blockDim.x) >> 6;
  float bias = lb[0];
  for (int m = wid; m < M_N; m += nw) {
    int iu = mu[m], is = ms[m];
    float p = u2[(size_t)iu * 128 + lane]      * lw[lane]
            + u2[(size_t)iu * 128 + 64 + lane] * lw[64 + lane]
            + s2[(size_t)is * 128 + lane]      * lw[128 + lane]
            + s2[(size_t)is * 128 + 64 + lane] * lw[192 + lane];
#pragma unroll
    for (int off = 32; off > 0; off >>= 1) p += __shfl_down(p, off, 64);
    if (lane == 0) out[m] = 1.0f / (1.0f + expf(-(p + bias)));
  }
}

extern "C" void kernel_launch(void* const* d_in, const int* in_sizes, int n_in,
                              void* d_out, int out_size, void* d_ws, size_t ws_size,
                              hipStream_t stream) {
  const float* xu   = (const float*)d_in[0];   // x_user_feat [NU,64]
  const float* xs   = (const float*)d_in[1];   // x_seller_feat [NS,64]
  const int*   x1   = (const int*)d_in[2];     // [NU,2]
  const int*   su   = (const int*)d_in[3];     // src_user [E]
  const int*   ds   = (const int*)d_in[4];     // dst_seller [E]
  const int*   ss   = (const int*)d_in[5];     // src_seller [E]
  const int*   du   = (const int*)d_in[6];     // dst_user [E]
  const int*   mu   = (const int*)d_in[7];     // mask_user [M]
  const int*   ms   = (const int*)d_in[8];     // mask_seller [M]
  const float* age  = (const float*)d_in[9];   // [9,32]
  const float* gen  = (const float*)d_in[10];  // [3,32]
  const float* W1ul = (const float*)d_in[11];  // [64,128]
  const float* W1ur = (const float*)d_in[12];  // [128,128]
  const float* b1u  = (const float*)d_in[13];
  const float* W1sl = (const float*)d_in[14];  // [128,128]
  const float* W1sr = (const float*)d_in[15];  // [64,128]
  const float* b1s  = (const float*)d_in[16];
  const float* W2ul = (const float*)d_in[17];
  const float* W2ur = (const float*)d_in[18];
  const float* b2u  = (const float*)d_in[19];
  const float* W2sl = (const float*)d_in[20];
  const float* W2sr = (const float*)d_in[21];
  const float* b2s  = (const float*)d_in[22];
  const float* lw   = (const float*)d_in[23];  // [256,1]
  const float* lb   = (const float*)d_in[24];  // [1]

  char* w = (char*)d_ws;
  float* aggU = (float*)(w + OFF_AGGU);
  float* aggS = (float*)(w + OFF_AGGS);
  float* cntU = (float*)(w + OFF_CNTU);
  float* cntS = (float*)(w + OFF_CNTS);
  float* ub   = (float*)(w + OFF_U);   // u1 then u2 (in-place)
  float* sb   = (float*)(w + OFF_S);   // s1 then s2 (in-place)
  float* ageW = (float*)(w + OFF_AGEW);
  float* genW = (float*)(w + OFF_GENW);
  float* out  = (float*)d_out;

  // ---- layer 1 ----
  hipMemsetAsync(aggU, 0, (size_t)NU_N * 64 * 4, stream);
  hipMemsetAsync(aggS, 0, (size_t)NS_N * 128 * 4, stream);
  hipMemsetAsync(cntU, 0, (size_t)NU_N * 4, stream);
  hipMemsetAsync(cntS, 0, (size_t)NS_N * 4, stream);

  build_tables_k<<<1, 128, 0, stream>>>(age, gen, W1ur, ageW, genW);
  scatter1_k<<<4096, 256, 0, stream>>>(su, ds, ss, du, xs, xu, x1, age, gen,
                                       aggU, aggS, cntU, cntS);
  rowgemm_k<<<2048, 128, 0, stream>>>(NU_N, aggU, cntU, 64, W1ul, xu, 64, W1ur, 64,
                                      b1u, ageW, genW, x1, ub);
  rowgemm_k<<<1024, 128, 0, stream>>>(NS_N, aggS, cntS, 128, W1sl, xs, 64, W1sr, 0,
                                      b1s, nullptr, nullptr, nullptr, sb);

  // ---- layer 2 (reuse agg buffers; stream order guarantees layer-1 reads done) ----
  hipMemsetAsync(aggU, 0, (size_t)NU_N * 128 * 4, stream);
  hipMemsetAsync(aggS, 0, (size_t)NS_N * 128 * 4, stream);
  scatter2_k<<<4096, 256, 0, stream>>>(su, ds, ss, du, ub, sb, aggU, aggS);
  rowgemm_k<<<2048, 128, 0, stream>>>(NU_N, aggU, cntU, 128, W2ul, ub, 128, W2ur, 0,
                                      b2u, nullptr, nullptr, nullptr, ub);
  rowgemm_k<<<1024, 128, 0, stream>>>(NS_N, aggS, cntS, 128, W2sl, sb, 128, W2sr, 0,
                                      b2s, nullptr, nullptr, nullptr, sb);

  // ---- final linear + sigmoid ----
  final_k<<<1024, 256, 0, stream>>>(ub, sb, mu, ms, lw, lb, out);
}

// Round 3
// 1918.093 us; speedup vs baseline: 2.0825x; 2.0825x over previous
//
#include <hip/hip_runtime.h>
#include <math.h>

#define NU_N 200000
#define NS_N 50000
#define E_N  1000000
#define M_N  100000

typedef __attribute__((ext_vector_type(8))) short short8;
typedef __attribute__((ext_vector_type(16))) float f32x16;

// ---- workspace layout (bytes) ----
static constexpr size_t OFF_AGGU  = 0;            // NU x 128 f32 max = 102,400,000
static constexpr size_t OFF_AGGS  = 102400000;    // NS x 128 f32 =  25,600,000
static constexpr size_t OFF_CNTU  = 128000000;    // NU f32
static constexpr size_t OFF_CNTS  = 128800000;    // NS f32
static constexpr size_t OFF_U     = 129000000;    // NU x 128 f32 (u1 then u2 in-place)
static constexpr size_t OFF_S     = 231400000;    // NS x 128 f32 (s1 then s2 in-place)
static constexpr size_t OFF_TBL27 = 257000000;    // 27 x 128 f32 = 13,824
static constexpr size_t OFF_WZ1U  = 257013824;    // K=128 swizzled bf16 = 32,768
static constexpr size_t OFF_WZ1S  = 257046592;    // K=192 -> 49,152
static constexpr size_t OFF_WZ2U  = 257095744;    // K=256 -> 65,536
static constexpr size_t OFF_WZ2S  = 257161280;    // K=256 -> 65,536

__device__ inline unsigned short f2bf(float f) {
  union { float f; unsigned u; } c; c.f = f;
  unsigned r = (c.u + 0x7FFFu + ((c.u >> 16) & 1u)) >> 16;
  return (unsigned short)r;
}

// combined per-(age,gender) bias table: tbl27[(a*3+g)*128+j] =
//   (age_emb[a] @ W1ur[0:32]) + (gen_emb[g] @ W1ur[32:64])  at column j
__global__ void build_tbl27_k(const float* __restrict__ age, const float* __restrict__ gen,
                              const float* __restrict__ W1ur, float* __restrict__ tbl27) {
  int j = threadIdx.x;  // 0..127
  float aw[9], gw[3];
  for (int a = 0; a < 9; ++a) {
    float acc = 0.f;
    for (int k = 0; k < 32; ++k) acc += age[a * 32 + k] * W1ur[k * 128 + j];
    aw[a] = acc;
  }
  for (int g = 0; g < 3; ++g) {
    float acc = 0.f;
    for (int k = 0; k < 32; ++k) acc += gen[g * 32 + k] * W1ur[(32 + k) * 128 + j];
    gw[g] = acc;
  }
  for (int t = 0; t < 27; ++t) tbl27[t * 128 + j] = aw[t / 3] + gw[t % 3];
}

// Swizzle W_cat ([K x 128], rows 0..Km-1 = Wl, rest = Wr[wrOff:]) into
// 32x32x16-bf16 B-fragment order: dst[((ct*NKT+kt)*64 + lane)*8 + j] =
//   bf16( Wcat[kt*16 + (lane>>5)*8 + j][ct*32 + (lane&31)] )
__global__ void wswz_k(const float* __restrict__ Wl, const float* __restrict__ Wr,
                       int Km, int wrOff, int K, unsigned short* __restrict__ dst) {
  int idx = blockIdx.x * blockDim.x + threadIdx.x;
  if (idx >= K * 128) return;
  int NKT = K / 16;
  int j = idx & 7, lane = (idx >> 3) & 63, rest = idx >> 9;
  int kt = rest % NKT, ct = rest / NKT;
  int k = kt * 16 + ((lane >> 5) << 3) + j;
  int n = ct * 32 + (lane & 31);
  float v = (k < Km) ? Wl[k * 128 + n] : Wr[(wrOff + k - Km) * 128 + n];
  dst[idx] = f2bf(v);
}

// Layer-1 edge scatter: one wave per edge (grid-stride).
__global__ void scatter1_k(const int* __restrict__ su, const int* __restrict__ ds,
                           const int* __restrict__ ss, const int* __restrict__ du,
                           const float* __restrict__ xs, const float* __restrict__ xu,
                           const int* __restrict__ x1,
                           const float* __restrict__ age, const float* __restrict__ gen,
                           float* __restrict__ aggU, float* __restrict__ aggS,
                           float* __restrict__ cntU, float* __restrict__ cntS) {
  int wid  = (blockIdx.x * blockDim.x + threadIdx.x) >> 6;
  int lane = threadIdx.x & 63;
  int nw   = (gridDim.x * blockDim.x) >> 6;
  for (int e = wid; e < E_N; e += nw) {
    int eu = su[e], es = ds[e], fs = ss[e], fu = du[e];
    atomicAdd(&aggU[(size_t)fu * 64 + lane], xs[(size_t)fs * 64 + lane]);
    int a = x1[2 * eu], g = x1[2 * eu + 1];
    float v0 = (lane < 32) ? age[a * 32 + lane] : gen[g * 32 + (lane - 32)];
    float v1 = xu[(size_t)eu * 64 + lane];
    atomicAdd(&aggS[(size_t)es * 128 + lane], v0);
    atomicAdd(&aggS[(size_t)es * 128 + 64 + lane], v1);
    if (lane == 0) {
      atomicAdd(&cntU[fu], 1.0f);
      atomicAdd(&cntS[es], 1.0f);
    }
  }
}

// Layer-2 edge scatter
__global__ void scatter2_k(const int* __restrict__ su, const int* __restrict__ ds,
                           const int* __restrict__ ss, const int* __restrict__ du,
                           const float* __restrict__ u1, const float* __restrict__ s1,
                           float* __restrict__ aggU, float* __restrict__ aggS) {
  int wid  = (blockIdx.x * blockDim.x + threadIdx.x) >> 6;
  int lane = threadIdx.x & 63;
  int nw   = (gridDim.x * blockDim.x) >> 6;
  for (int e = wid; e < E_N; e += nw) {
    int eu = su[e], es = ds[e], fs = ss[e], fu = du[e];
    atomicAdd(&aggU[(size_t)fu * 128 + lane],      s1[(size_t)fs * 128 + lane]);
    atomicAdd(&aggU[(size_t)fu * 128 + 64 + lane], s1[(size_t)fs * 128 + 64 + lane]);
    atomicAdd(&aggS[(size_t)es * 128 + lane],      u1[(size_t)eu * 128 + lane]);
    atomicAdd(&aggS[(size_t)es * 128 + 64 + lane], u1[(size_t)eu * 128 + 64 + lane]);
  }
}

// MFMA row-GEMM: out[M x 128] = relu( [meanScaled | self] @ Wswz + bias (+ tbl27) )
// block = 256 thr = 4 waves; block covers 256 rows; wave covers 64 rows
// (2 row-tiles of 32), 4 col-tiles of 32. mfma_f32_32x32x16_bf16.
// self/out may alias (in-place layer 2): each wave reads only its own rows
// during the K-loop and writes them only in the epilogue.
template <int KM, int KS, bool TBL>
__global__ __launch_bounds__(256, 2) void gemm_mfma_k(
    int nrows, const float* __restrict__ agg, const float* __restrict__ cnt,
    const float* self, const unsigned short* __restrict__ wswz,
    const float* __restrict__ bias, const float* __restrict__ tbl27,
    const int* __restrict__ x1, float* out) {
  constexpr int K = KM + KS;
  constexpr int NKT = K / 16;
  __shared__ short sW[K * 128];

  // stage swizzled weights (bf16) to LDS
  {
    const uint4* g4 = (const uint4*)wswz;
    uint4* s4 = (uint4*)sW;
    for (int i = threadIdx.x; i < K * 16; i += 256) s4[i] = g4[i];
  }
  __syncthreads();

  int wave = threadIdx.x >> 6, lane = threadIdx.x & 63;
  int r0 = blockIdx.x * 256 + wave * 64;
  int qk = (lane >> 5) << 3;  // this lane's k sub-offset (0 or 8)

  int ra = r0 + (lane & 31), rb = ra + 32;
  bool va = ra < nrows, vb = rb < nrows;
  int rac = va ? ra : 0, rbc = vb ? rb : 0;
  float invA = va ? 1.0f / fmaxf(cnt[rac], 1.0f) : 0.0f;
  float invB = vb ? 1.0f / fmaxf(cnt[rbc], 1.0f) : 0.0f;
  float selfA = va ? 1.0f : 0.0f, selfB = vb ? 1.0f : 0.0f;

  f32x16 acc[2][4];
#pragma unroll
  for (int rt = 0; rt < 2; ++rt)
#pragma unroll
    for (int ct = 0; ct < 4; ++ct) acc[rt][ct] = (f32x16)0.0f;

  const short8* sWv = (const short8*)sW;

  for (int kt = 0; kt < NKT; ++kt) {
    int k0 = kt * 16 + qk;
    bool isMean = (k0 < KM);  // wave-uniform (KM % 16 == 0)
    const float* pa;
    const float* pb;
    float sa, sb_;
    if (isMean) {
      pa = agg + (size_t)rac * KM + k0;
      pb = agg + (size_t)rbc * KM + k0;
      sa = invA; sb_ = invB;
    } else {
      pa = self + (size_t)rac * KS + (k0 - KM);
      pb = self + (size_t)rbc * KS + (k0 - KM);
      sa = selfA; sb_ = selfB;
    }
    float4 a0 = ((const float4*)pa)[0], a1 = ((const float4*)pa)[1];
    float4 b0 = ((const float4*)pb)[0], b1 = ((const float4*)pb)[1];
    short8 af, bf;
    af[0] = f2bf(a0.x * sa); af[1] = f2bf(a0.y * sa);
    af[2] = f2bf(a0.z * sa); af[3] = f2bf(a0.w * sa);
    af[4] = f2bf(a1.x * sa); af[5] = f2bf(a1.y * sa);
    af[6] = f2bf(a1.z * sa); af[7] = f2bf(a1.w * sa);
    bf[0] = f2bf(b0.x * sb_); bf[1] = f2bf(b0.y * sb_);
    bf[2] = f2bf(b0.z * sb_); bf[3] = f2bf(b0.w * sb_);
    bf[4] = f2bf(b1.x * sb_); bf[5] = f2bf(b1.y * sb_);
    bf[6] = f2bf(b1.z * sb_); bf[7] = f2bf(b1.w * sb_);
#pragma unroll
    for (int ct = 0; ct < 4; ++ct) {
      short8 wf = sWv[(ct * NKT + kt) * 64 + lane];
      acc[0][ct] = __builtin_amdgcn_mfma_f32_32x32x16_bf16(af, wf, acc[0][ct], 0, 0, 0);
      acc[1][ct] = __builtin_amdgcn_mfma_f32_32x32x16_bf16(bf, wf, acc[1][ct], 0, 0, 0);
    }
  }

  // epilogue: bias (+tbl27) + relu + store (C layout: col=lane&31,
  // row = (reg&3) + 8*(reg>>2) + 4*(lane>>5))
  int nloc = lane & 31;
  float bn[4];
#pragma unroll
  for (int ct = 0; ct < 4; ++ct) bn[ct] = bias[ct * 32 + nloc];
  int rowq = 4 * (lane >> 5);
#pragma unroll
  for (int rt = 0; rt < 2; ++rt) {
#pragma unroll
    for (int reg = 0; reg < 16; ++reg) {
      int row = r0 + rt * 32 + (reg & 3) + 8 * (reg >> 2) + rowq;
      if (row < nrows) {
        const float* tp = nullptr;
        if (TBL) {
          int a = x1[2 * row], g = x1[2 * row + 1];
          tp = tbl27 + (a * 3 + g) * 128 + nloc;
        }
#pragma unroll
        for (int ct = 0; ct < 4; ++ct) {
          float v = acc[rt][ct][reg] + bn[ct];
          if (TBL) v += tp[ct * 32];
          out[(size_t)row * 128 + ct * 32 + nloc] = fmaxf(v, 0.0f);
        }
      }
    }
  }
}

// Final: out[m] = sigmoid(u2[mu[m]] . lw[0:128] + s2[ms[m]] . lw[128:256] + lb)
__global__ void final_k(const float* __restrict__ u2, const float* __restrict__ s2,
                        const int* __restrict__ mu, const int* __restrict__ ms,
                        const float* __restrict__ lw, const float* __restrict__ lb,
                        float* __restrict__ out) {
  int wid  = (blockIdx.x * blockDim.x + threadIdx.x) >> 6;
  int lane = threadIdx.x & 63;
  int nw   = (gridDim.x * blockDim.x) >> 6;
  float bias = lb[0];
  for (int m = wid; m < M_N; m += nw) {
    int iu = mu[m], is = ms[m];
    float p = u2[(size_t)iu * 128 + lane]      * lw[lane]
            + u2[(size_t)iu * 128 + 64 + lane] * lw[64 + lane]
            + s2[(size_t)is * 128 + lane]      * lw[128 + lane]
            + s2[(size_t)is * 128 + 64 + lane] * lw[192 + lane];
#pragma unroll
    for (int off = 32; off > 0; off >>= 1) p += __shfl_down(p, off, 64);
    if (lane == 0) out[m] = 1.0f / (1.0f + expf(-(p + bias)));
  }
}

extern "C" void kernel_launch(void* const* d_in, const int* in_sizes, int n_in,
                              void* d_out, int out_size, void* d_ws, size_t ws_size,
                              hipStream_t stream) {
  const float* xu   = (const float*)d_in[0];
  const float* xs   = (const float*)d_in[1];
  const int*   x1   = (const int*)d_in[2];
  const int*   su   = (const int*)d_in[3];
  const int*   ds   = (const int*)d_in[4];
  const int*   ss   = (const int*)d_in[5];
  const int*   du   = (const int*)d_in[6];
  const int*   mu   = (const int*)d_in[7];
  const int*   ms   = (const int*)d_in[8];
  const float* age  = (const float*)d_in[9];
  const float* gen  = (const float*)d_in[10];
  const float* W1ul = (const float*)d_in[11];
  const float* W1ur = (const float*)d_in[12];
  const float* b1u  = (const float*)d_in[13];
  const float* W1sl = (const float*)d_in[14];
  const float* W1sr = (const float*)d_in[15];
  const float* b1s  = (const float*)d_in[16];
  const float* W2ul = (const float*)d_in[17];
  const float* W2ur = (const float*)d_in[18];
  const float* b2u  = (const float*)d_in[19];
  const float* W2sl = (const float*)d_in[20];
  const float* W2sr = (const float*)d_in[21];
  const float* b2s  = (const float*)d_in[22];
  const float* lw   = (const float*)d_in[23];
  const float* lb   = (const float*)d_in[24];

  char* w = (char*)d_ws;
  float* aggU = (float*)(w + OFF_AGGU);
  float* aggS = (float*)(w + OFF_AGGS);
  float* cntU = (float*)(w + OFF_CNTU);
  float* cntS = (float*)(w + OFF_CNTS);
  float* ub   = (float*)(w + OFF_U);
  float* sb   = (float*)(w + OFF_S);
  float* tbl27 = (float*)(w + OFF_TBL27);
  unsigned short* wz1u = (unsigned short*)(w + OFF_WZ1U);
  unsigned short* wz1s = (unsigned short*)(w + OFF_WZ1S);
  unsigned short* wz2u = (unsigned short*)(w + OFF_WZ2U);
  unsigned short* wz2s = (unsigned short*)(w + OFF_WZ2S);
  float* out = (float*)d_out;

  // ---- prep: tables + swizzled bf16 weights ----
  build_tbl27_k<<<1, 128, 0, stream>>>(age, gen, W1ur, tbl27);
  wswz_k<<<(128 * 128 + 255) / 256, 256, 0, stream>>>(W1ul, W1ur, 64, 64, 128, wz1u);
  wswz_k<<<(192 * 128 + 255) / 256, 256, 0, stream>>>(W1sl, W1sr, 128, 0, 192, wz1s);
  wswz_k<<<(256 * 128 + 255) / 256, 256, 0, stream>>>(W2ul, W2ur, 128, 0, 256, wz2u);
  wswz_k<<<(256 * 128 + 255) / 256, 256, 0, stream>>>(W2sl, W2sr, 128, 0, 256, wz2s);

  // ---- layer 1 ----
  hipMemsetAsync(aggU, 0, (size_t)NU_N * 64 * 4, stream);
  hipMemsetAsync(aggS, 0, (size_t)NS_N * 128 * 4, stream);
  hipMemsetAsync(cntU, 0, (size_t)NU_N * 4, stream);
  hipMemsetAsync(cntS, 0, (size_t)NS_N * 4, stream);
  scatter1_k<<<4096, 256, 0, stream>>>(su, ds, ss, du, xs, xu, x1, age, gen,
                                       aggU, aggS, cntU, cntS);
  gemm_mfma_k<64, 64, true><<<(NU_N + 255) / 256, 256, 0, stream>>>(
      NU_N, aggU, cntU, xu, wz1u, b1u, tbl27, x1, ub);
  gemm_mfma_k<128, 64, false><<<(NS_N + 255) / 256, 256, 0, stream>>>(
      NS_N, aggS, cntS, xs, wz1s, b1s, nullptr, nullptr, sb);

  // ---- layer 2 ----
  hipMemsetAsync(aggU, 0, (size_t)NU_N * 128 * 4, stream);
  hipMemsetAsync(aggS, 0, (size_t)NS_N * 128 * 4, stream);
  scatter2_k<<<4096, 256, 0, stream>>>(su, ds, ss, du, ub, sb, aggU, aggS);
  gemm_mfma_k<128, 128, false><<<(NU_N + 255) / 256, 256, 0, stream>>>(
      NU_N, aggU, cntU, ub, wz2u, b2u, nullptr, nullptr, ub);
  gemm_mfma_k<128, 128, false><<<(NS_N + 255) / 256, 256, 0, stream>>>(
      NS_N, aggS, cntS, sb, wz2s, b2s, nullptr, nullptr, sb);

  // ---- final linear + sigmoid ----
  final_k<<<1024, 256, 0, stream>>>(ub, sb, mu, ms, lw, lb, out);
}

// Round 4
// 992.012 us; speedup vs baseline: 4.0267x; 1.9335x over previous
//
#include <hip/hip_runtime.h>
#include <math.h>

#define NU_N 200000
#define NS_N 50000
#define E_N  1000000
#define M_N  100000

typedef __attribute__((ext_vector_type(8))) short short8;
typedef __attribute__((ext_vector_type(16))) float f32x16;
typedef unsigned short ushort_t;
typedef unsigned int uint_t;

// ---- workspace layout (bytes), total ~139 MB ----
static constexpr size_t OFF_AGGU  = 0;            // NU x 128 bf16 = 51,200,000
static constexpr size_t OFF_AGGS  = 51200000;     // NS x 128 bf16 = 12,800,000
static constexpr size_t OFF_U     = 64000000;     // NU x 128 bf16 (u1 then u2 in-place)
static constexpr size_t OFF_S     = 115200000;    // NS x 128 bf16
static constexpr size_t OFF_TBL27 = 128000000;    // 27 x 128 f32
static constexpr size_t OFF_WZ1U  = 128013824;    // K=128 swizzled bf16
static constexpr size_t OFF_WZ1S  = 128046592;    // K=192
static constexpr size_t OFF_WZ2U  = 128095744;    // K=256
static constexpr size_t OFF_WZ2S  = 128161280;    // K=256
static constexpr size_t OFF_RPU   = 128226816;    // (NU+1) int
static constexpr size_t OFF_RPS   = 129026848;    // (NS+1) int
static constexpr size_t OFF_CSRU  = 129226880;    // E int (seller srcs, dst=user)
static constexpr size_t OFF_CSRS  = 133226880;    // E int (user srcs, dst=seller)
static constexpr size_t OFF_HISTU = 137226880;    // NU int
static constexpr size_t OFF_HISTS = 138026880;    // NS int
static constexpr size_t OFF_CURU  = 138226880;    // NU int
static constexpr size_t OFF_CURS  = 139026880;    // NS int
static constexpr size_t OFF_PART  = 139226880;    // 1024 int

__device__ inline ushort_t f2bf(float f) {
  union { float f; uint_t u; } c; c.f = f;
  uint_t r = (c.u + 0x7FFFu + ((c.u >> 16) & 1u)) >> 16;
  return (ushort_t)r;
}
__device__ inline float bf2f(uint_t u) {
  union { uint_t u; float f; } c; c.u = u << 16;
  return c.f;
}

// ===================== CSR build =====================
__global__ void hist_k(const int* __restrict__ du, const int* __restrict__ ds,
                       int* __restrict__ histU, int* __restrict__ histS) {
  int e = blockIdx.x * blockDim.x + threadIdx.x;
  if (e >= E_N) return;
  atomicAdd(&histU[du[e]], 1);
  atomicAdd(&histS[ds[e]], 1);
}

// inclusive scan of w[i] (w[0]=0, w[i]=hist[i-1]) -> exclusive scan of hist
__global__ void scan1_k(const int* __restrict__ hist, int n, int* __restrict__ rowptr,
                        int* __restrict__ part) {
  __shared__ int s[256];
  int t = threadIdx.x;
  int idx = blockIdx.x * 256 + t;
  int v = (idx > 0 && idx < n) ? hist[idx - 1] : 0;
  s[t] = v;
  __syncthreads();
  for (int off = 1; off < 256; off <<= 1) {
    int x = (t >= off) ? s[t - off] : 0;
    __syncthreads();
    s[t] += x;
    __syncthreads();
  }
  if (idx < n) rowptr[idx] = s[t];
  if (t == 255) part[blockIdx.x] = s[255];
}

__global__ void scan2_k(int* __restrict__ part, int nb) {
  __shared__ int s[1024];
  int t = threadIdx.x;
  int v = (t < nb) ? part[t] : 0;
  s[t] = v;
  __syncthreads();
  for (int off = 1; off < 1024; off <<= 1) {
    int x = (t >= off) ? s[t - off] : 0;
    __syncthreads();
    s[t] += x;
    __syncthreads();
  }
  if (t < nb) part[t] = s[t] - v;  // exclusive
}

__global__ void scan3_k(int* __restrict__ rowptr, int n, const int* __restrict__ part) {
  int idx = blockIdx.x * 256 + threadIdx.x;
  if (idx < n) rowptr[idx] += part[blockIdx.x];
}

__global__ void fill_k(const int* __restrict__ su, const int* __restrict__ ds,
                       const int* __restrict__ ss, const int* __restrict__ du,
                       const int* __restrict__ rpU, const int* __restrict__ rpS,
                       int* __restrict__ curU, int* __restrict__ curS,
                       int* __restrict__ csrU, int* __restrict__ csrS) {
  int e = blockIdx.x * blockDim.x + threadIdx.x;
  if (e >= E_N) return;
  int u = du[e];
  int p = atomicAdd(&curU[u], 1);
  csrU[rpU[u] + p] = ss[e];
  int s = ds[e];
  int q = atomicAdd(&curS[s], 1);
  csrS[rpS[s] + q] = su[e];
}

// ===================== prep: tables + weight swizzle =====================
__global__ void build_tbl27_k(const float* __restrict__ age, const float* __restrict__ gen,
                              const float* __restrict__ W1ur, float* __restrict__ tbl27) {
  int j = threadIdx.x;  // 0..127
  float aw[9], gw[3];
  for (int a = 0; a < 9; ++a) {
    float acc = 0.f;
    for (int k = 0; k < 32; ++k) acc += age[a * 32 + k] * W1ur[k * 128 + j];
    aw[a] = acc;
  }
  for (int g = 0; g < 3; ++g) {
    float acc = 0.f;
    for (int k = 0; k < 32; ++k) acc += gen[g * 32 + k] * W1ur[(32 + k) * 128 + j];
    gw[g] = acc;
  }
  for (int t = 0; t < 27; ++t) tbl27[t * 128 + j] = aw[t / 3] + gw[t % 3];
}

// dst[((ct*NKT+kt)*64 + lane)*8 + j] = bf16(Wcat[kt*16+(lane>>5)*8+j][ct*32+(lane&31)])
__global__ void wswz_k(const float* __restrict__ Wl, const float* __restrict__ Wr,
                       int Km, int wrOff, int K, ushort_t* __restrict__ dst) {
  int idx = blockIdx.x * blockDim.x + threadIdx.x;
  if (idx >= K * 128) return;
  int NKT = K / 16;
  int j = idx & 7, lane = (idx >> 3) & 63, rest = idx >> 9;
  int kt = rest % NKT, ct = rest / NKT;
  int k = kt * 16 + ((lane >> 5) << 3) + j;
  int n = ct * 32 + (lane & 31);
  float v = (k < Km) ? Wl[k * 128 + n] : Wr[(wrOff + k - Km) * 128 + n];
  dst[idx] = f2bf(v);
}

// ===================== gathers (mean over CSR neighbors) =====================
// layer1 user: mean of seller feats (f32, 64-d) -> bf16 [NU x 64]
__global__ void gather1u_k(const int* __restrict__ rp, const int* __restrict__ csr,
                           const float* __restrict__ xs, ushort_t* __restrict__ agg) {
  int w = (blockIdx.x * blockDim.x + threadIdx.x) >> 6;
  int lane = threadIdx.x & 63;
  if (w >= NU_N) return;
  int b = rp[w], e = rp[w + 1];
  float a = 0.f;
  for (int i = b; i < e; ++i) {
    int j = csr[i];
    a += xs[(size_t)j * 64 + lane];
  }
  float inv = 1.0f / fmaxf((float)(e - b), 1.0f);
  agg[(size_t)w * 64 + lane] = f2bf(a * inv);
}

// layer1 seller: mean of x_u = [age||gen||xu] (128-d) -> bf16 [NS x 128]
__global__ void gather1s_k(const int* __restrict__ rp, const int* __restrict__ csr,
                           const float* __restrict__ xu, const int* __restrict__ x1,
                           const float* __restrict__ age, const float* __restrict__ gen,
                           ushort_t* __restrict__ agg) {
  int w = (blockIdx.x * blockDim.x + threadIdx.x) >> 6;
  int lane = threadIdx.x & 63;
  if (w >= NS_N) return;
  int b = rp[w], e = rp[w + 1];
  float a0 = 0.f, a1 = 0.f;
  for (int i = b; i < e; ++i) {
    int j = csr[i];
    int av = x1[2 * j], gv = x1[2 * j + 1];
    a0 += (lane < 32) ? age[av * 32 + lane] : gen[gv * 32 + (lane - 32)];
    a1 += xu[(size_t)j * 64 + lane];
  }
  float inv = 1.0f / fmaxf((float)(e - b), 1.0f);
  agg[(size_t)w * 128 + lane] = f2bf(a0 * inv);
  agg[(size_t)w * 128 + 64 + lane] = f2bf(a1 * inv);
}

// layer2: mean of bf16 128-d rows
__global__ void gather2_k(int ndst, const int* __restrict__ rp, const int* __restrict__ csr,
                          const ushort_t* __restrict__ src, ushort_t* __restrict__ dst) {
  int w = (blockIdx.x * blockDim.x + threadIdx.x) >> 6;
  int lane = threadIdx.x & 63;
  if (w >= ndst) return;
  int b = rp[w], e = rp[w + 1];
  float a0 = 0.f, a1 = 0.f;
  for (int i = b; i < e; ++i) {
    int j = csr[i];
    uint_t v = ((const uint_t*)(src + (size_t)j * 128))[lane];
    a0 += bf2f(v & 0xffffu);
    a1 += bf2f(v >> 16);
  }
  float inv = 1.0f / fmaxf((float)(e - b), 1.0f);
  uint_t o = (uint_t)f2bf(a0 * inv) | ((uint_t)f2bf(a1 * inv) << 16);
  ((uint_t*)(dst + (size_t)w * 128))[lane] = o;
}

// ===================== MFMA row-GEMM =====================
// out[M x 128] = relu( [mean(bf16) | self] @ Wswz + bias (+ tbl27) ), out bf16.
// block = 4 waves = 256 rows; wave: 2 row-tiles x 4 col-tiles of 32x32x16 MFMA.
// self/out may alias (in-place layer 2): wave reads only its own rows in the
// K-loop, writes them only in the epilogue.
template <int KM, int KS, bool TBL, bool SELF_BF16>
__global__ __launch_bounds__(256, 2) void gemm_mfma_k(
    int nrows, const ushort_t* __restrict__ agg, const void* self,
    const ushort_t* __restrict__ wswz, const float* __restrict__ bias,
    const float* __restrict__ tbl27, const int* __restrict__ x1, ushort_t* out) {
  constexpr int K = KM + KS;
  constexpr int NKT = K / 16;
  __shared__ short sW[K * 128];

  {
    const uint4* g4 = (const uint4*)wswz;
    uint4* s4 = (uint4*)sW;
    for (int i = threadIdx.x; i < K * 16; i += 256) s4[i] = g4[i];
  }
  __syncthreads();

  int wave = threadIdx.x >> 6, lane = threadIdx.x & 63;
  int r0 = blockIdx.x * 256 + wave * 64;
  int qk = (lane >> 5) << 3;  // k sub-offset (0 or 8)

  int ra = r0 + (lane & 31), rb = ra + 32;
  int rac = (ra < nrows) ? ra : 0, rbc = (rb < nrows) ? rb : 0;

  f32x16 acc[2][4];
#pragma unroll
  for (int rt = 0; rt < 2; ++rt)
#pragma unroll
    for (int ct = 0; ct < 4; ++ct) acc[rt][ct] = (f32x16)0.0f;

  const short8* sWv = (const short8*)sW;

#pragma unroll
  for (int kt = 0; kt < NKT; ++kt) {
    int k0 = kt * 16 + qk;
    short8 af, bf;
    if (kt * 16 < KM) {  // compile-time: mean part (KM % 16 == 0)
      af = *((const short8*)(agg + (size_t)rac * KM + k0));
      bf = *((const short8*)(agg + (size_t)rbc * KM + k0));
    } else if (SELF_BF16) {
      const ushort_t* sp = (const ushort_t*)self;
      af = *((const short8*)(sp + (size_t)rac * KS + (k0 - KM)));
      bf = *((const short8*)(sp + (size_t)rbc * KS + (k0 - KM)));
    } else {
      const float* pa = (const float*)self + (size_t)rac * KS + (k0 - KM);
      const float* pb = (const float*)self + (size_t)rbc * KS + (k0 - KM);
      float4 a0 = ((const float4*)pa)[0], a1 = ((const float4*)pa)[1];
      float4 b0 = ((const float4*)pb)[0], b1 = ((const float4*)pb)[1];
      af[0] = f2bf(a0.x); af[1] = f2bf(a0.y); af[2] = f2bf(a0.z); af[3] = f2bf(a0.w);
      af[4] = f2bf(a1.x); af[5] = f2bf(a1.y); af[6] = f2bf(a1.z); af[7] = f2bf(a1.w);
      bf[0] = f2bf(b0.x); bf[1] = f2bf(b0.y); bf[2] = f2bf(b0.z); bf[3] = f2bf(b0.w);
      bf[4] = f2bf(b1.x); bf[5] = f2bf(b1.y); bf[6] = f2bf(b1.z); bf[7] = f2bf(b1.w);
    }
#pragma unroll
    for (int ct = 0; ct < 4; ++ct) {
      short8 wf = sWv[(ct * NKT + kt) * 64 + lane];
      acc[0][ct] = __builtin_amdgcn_mfma_f32_32x32x16_bf16(af, wf, acc[0][ct], 0, 0, 0);
      acc[1][ct] = __builtin_amdgcn_mfma_f32_32x32x16_bf16(bf, wf, acc[1][ct], 0, 0, 0);
    }
  }

  // epilogue: C layout col=lane&31, row=(reg&3)+8*(reg>>2)+4*(lane>>5)
  int nloc = lane & 31;
  float bn[4];
#pragma unroll
  for (int ct = 0; ct < 4; ++ct) bn[ct] = bias[ct * 32 + nloc];
  int rowq = 4 * (lane >> 5);
#pragma unroll
  for (int rt = 0; rt < 2; ++rt) {
#pragma unroll
    for (int reg = 0; reg < 16; ++reg) {
      int row = r0 + rt * 32 + (reg & 3) + 8 * (reg >> 2) + rowq;
      if (row < nrows) {
        const float* tp = nullptr;
        if (TBL) {
          int a = x1[2 * row], g = x1[2 * row + 1];
          tp = tbl27 + (a * 3 + g) * 128 + nloc;
        }
#pragma unroll
        for (int ct = 0; ct < 4; ++ct) {
          float v = acc[rt][ct][reg] + bn[ct];
          if (TBL) v += tp[ct * 32];
          out[(size_t)row * 128 + ct * 32 + nloc] = f2bf(fmaxf(v, 0.0f));
        }
      }
    }
  }
}

// ===================== final =====================
__global__ void final_k(const ushort_t* __restrict__ u2, const ushort_t* __restrict__ s2,
                        const int* __restrict__ mu, const int* __restrict__ ms,
                        const float* __restrict__ lw, const float* __restrict__ lb,
                        float* __restrict__ out) {
  int w = (blockIdx.x * blockDim.x + threadIdx.x) >> 6;
  int lane = threadIdx.x & 63;
  if (w >= M_N) return;
  int iu = mu[w], is = ms[w];
  uint_t a = ((const uint_t*)(u2 + (size_t)iu * 128))[lane];
  uint_t b = ((const uint_t*)(s2 + (size_t)is * 128))[lane];
  float p = bf2f(a & 0xffffu) * lw[2 * lane] + bf2f(a >> 16) * lw[2 * lane + 1]
          + bf2f(b & 0xffffu) * lw[128 + 2 * lane] + bf2f(b >> 16) * lw[129 + 2 * lane];
#pragma unroll
  for (int off = 32; off > 0; off >>= 1) p += __shfl_down(p, off, 64);
  if (lane == 0) out[w] = 1.0f / (1.0f + expf(-(p + lb[0])));
}

extern "C" void kernel_launch(void* const* d_in, const int* in_sizes, int n_in,
                              void* d_out, int out_size, void* d_ws, size_t ws_size,
                              hipStream_t stream) {
  const float* xu   = (const float*)d_in[0];
  const float* xs   = (const float*)d_in[1];
  const int*   x1   = (const int*)d_in[2];
  const int*   su   = (const int*)d_in[3];
  const int*   ds   = (const int*)d_in[4];
  const int*   ss   = (const int*)d_in[5];
  const int*   du   = (const int*)d_in[6];
  const int*   mu   = (const int*)d_in[7];
  const int*   ms   = (const int*)d_in[8];
  const float* age  = (const float*)d_in[9];
  const float* gen  = (const float*)d_in[10];
  const float* W1ul = (const float*)d_in[11];
  const float* W1ur = (const float*)d_in[12];
  const float* b1u  = (const float*)d_in[13];
  const float* W1sl = (const float*)d_in[14];
  const float* W1sr = (const float*)d_in[15];
  const float* b1s  = (const float*)d_in[16];
  const float* W2ul = (const float*)d_in[17];
  const float* W2ur = (const float*)d_in[18];
  const float* b2u  = (const float*)d_in[19];
  const float* W2sl = (const float*)d_in[20];
  const float* W2sr = (const float*)d_in[21];
  const float* b2s  = (const float*)d_in[22];
  const float* lw   = (const float*)d_in[23];
  const float* lb   = (const float*)d_in[24];

  char* w = (char*)d_ws;
  ushort_t* aggU = (ushort_t*)(w + OFF_AGGU);
  ushort_t* aggS = (ushort_t*)(w + OFF_AGGS);
  ushort_t* ub   = (ushort_t*)(w + OFF_U);
  ushort_t* sb   = (ushort_t*)(w + OFF_S);
  float* tbl27   = (float*)(w + OFF_TBL27);
  ushort_t* wz1u = (ushort_t*)(w + OFF_WZ1U);
  ushort_t* wz1s = (ushort_t*)(w + OFF_WZ1S);
  ushort_t* wz2u = (ushort_t*)(w + OFF_WZ2U);
  ushort_t* wz2s = (ushort_t*)(w + OFF_WZ2S);
  int* rpU   = (int*)(w + OFF_RPU);
  int* rpS   = (int*)(w + OFF_RPS);
  int* csrU  = (int*)(w + OFF_CSRU);
  int* csrS  = (int*)(w + OFF_CSRS);
  int* histU = (int*)(w + OFF_HISTU);
  int* histS = (int*)(w + OFF_HISTS);
  int* curU  = (int*)(w + OFF_CURU);
  int* curS  = (int*)(w + OFF_CURS);
  int* part  = (int*)(w + OFF_PART);
  float* out = (float*)d_out;

  const int EB = (E_N + 255) / 256;
  const int NBU = (NU_N + 1 + 255) / 256;   // 782
  const int NBS = (NS_N + 1 + 255) / 256;   // 196

  // ---- CSR build (once; shared by both layers) ----
  hipMemsetAsync(histU, 0, NU_N * 4, stream);
  hipMemsetAsync(histS, 0, NS_N * 4, stream);
  hipMemsetAsync(curU, 0, NU_N * 4, stream);
  hipMemsetAsync(curS, 0, NS_N * 4, stream);
  hist_k<<<EB, 256, 0, stream>>>(du, ds, histU, histS);
  scan1_k<<<NBU, 256, 0, stream>>>(histU, NU_N + 1, rpU, part);
  scan2_k<<<1, 1024, 0, stream>>>(part, NBU);
  scan3_k<<<NBU, 256, 0, stream>>>(rpU, NU_N + 1, part);
  scan1_k<<<NBS, 256, 0, stream>>>(histS, NS_N + 1, rpS, part);
  scan2_k<<<1, 1024, 0, stream>>>(part, NBS);
  scan3_k<<<NBS, 256, 0, stream>>>(rpS, NS_N + 1, part);
  fill_k<<<EB, 256, 0, stream>>>(su, ds, ss, du, rpU, rpS, curU, curS, csrU, csrS);

  // ---- prep: tables + swizzled bf16 weights ----
  build_tbl27_k<<<1, 128, 0, stream>>>(age, gen, W1ur, tbl27);
  wswz_k<<<(128 * 128 + 255) / 256, 256, 0, stream>>>(W1ul, W1ur, 64, 64, 128, wz1u);
  wswz_k<<<(192 * 128 + 255) / 256, 256, 0, stream>>>(W1sl, W1sr, 128, 0, 192, wz1s);
  wswz_k<<<(256 * 128 + 255) / 256, 256, 0, stream>>>(W2ul, W2ur, 128, 0, 256, wz2u);
  wswz_k<<<(256 * 128 + 255) / 256, 256, 0, stream>>>(W2sl, W2sr, 128, 0, 256, wz2s);

  // ---- layer 1 ----
  gather1u_k<<<NU_N / 4, 256, 0, stream>>>(rpU, csrU, xs, aggU);
  gather1s_k<<<NS_N / 4, 256, 0, stream>>>(rpS, csrS, xu, x1, age, gen, aggS);
  gemm_mfma_k<64, 64, true, false><<<(NU_N + 255) / 256, 256, 0, stream>>>(
      NU_N, aggU, xu, wz1u, b1u, tbl27, x1, ub);
  gemm_mfma_k<128, 64, false, false><<<(NS_N + 255) / 256, 256, 0, stream>>>(
      NS_N, aggS, xs, wz1s, b1s, nullptr, nullptr, sb);

  // ---- layer 2 ----
  gather2_k<<<NU_N / 4, 256, 0, stream>>>(NU_N, rpU, csrU, sb, aggU);
  gather2_k<<<NS_N / 4, 256, 0, stream>>>(NS_N, rpS, csrS, ub, aggS);
  gemm_mfma_k<128, 128, false, true><<<(NU_N + 255) / 256, 256, 0, stream>>>(
      NU_N, aggU, ub, wz2u, b2u, nullptr, nullptr, ub);
  gemm_mfma_k<128, 128, false, true><<<(NS_N + 255) / 256, 256, 0, stream>>>(
      NS_N, aggS, sb, wz2s, b2s, nullptr, nullptr, sb);

  // ---- final linear + sigmoid ----
  final_k<<<(M_N * 64 + 255) / 256, 256, 0, stream>>>(ub, sb, mu, ms, lw, lb, out);
}

// Round 5
// 750.862 us; speedup vs baseline: 5.3199x; 1.3212x over previous
//
#include <hip/hip_runtime.h>
#include <math.h>

#define NU_N 200000
#define NS_N 50000
#define E_N  1000000
#define M_N  100000

typedef __attribute__((ext_vector_type(8))) short short8;
typedef __attribute__((ext_vector_type(16))) float f32x16;
typedef unsigned short ushort_t;
typedef unsigned int uint_t;

// ---- workspace layout (bytes), total ~139 MB ----
static constexpr size_t OFF_AGGU  = 0;            // NU x 128 bf16 = 51,200,000
static constexpr size_t OFF_AGGS  = 51200000;     // NS x 128 bf16 = 12,800,000
static constexpr size_t OFF_U     = 64000000;     // NU x 128 bf16 (u1 then u2 in-place)
static constexpr size_t OFF_S     = 115200000;    // NS x 128 bf16
static constexpr size_t OFF_TBL27 = 128000000;    // 27 x 128 f32
static constexpr size_t OFF_WZ1U  = 128013824;    // K=128 swizzled bf16
static constexpr size_t OFF_WZ1S  = 128046592;    // K=192
static constexpr size_t OFF_WZ2U  = 128095744;    // K=256
static constexpr size_t OFF_WZ2S  = 128161280;    // K=256
static constexpr size_t OFF_RPU   = 128226816;    // (NU+1) int
static constexpr size_t OFF_RPS   = 129026848;    // (NS+1) int
static constexpr size_t OFF_CSRU  = 129226880;    // E int (seller srcs, dst=user)
static constexpr size_t OFF_CSRS  = 133226880;    // E int (user srcs, dst=seller)
static constexpr size_t OFF_HISTU = 137226880;    // NU int
static constexpr size_t OFF_HISTS = 138026880;    // NS int
static constexpr size_t OFF_CURU  = 138226880;    // NU int
static constexpr size_t OFF_CURS  = 139026880;    // NS int
static constexpr size_t OFF_PART  = 139226880;    // 1024 int

__device__ inline ushort_t f2bf(float f) {
  union { float f; uint_t u; } c; c.f = f;
  uint_t r = (c.u + 0x7FFFu + ((c.u >> 16) & 1u)) >> 16;
  return (ushort_t)r;
}
__device__ inline float bf2f(uint_t u) {
  union { uint_t u; float f; } c; c.u = u << 16;
  return c.f;
}

// ===================== CSR build =====================
__global__ void hist_k(const int* __restrict__ du, const int* __restrict__ ds,
                       int* __restrict__ histU, int* __restrict__ histS) {
  int e = blockIdx.x * blockDim.x + threadIdx.x;
  if (e >= E_N) return;
  atomicAdd(&histU[du[e]], 1);
  atomicAdd(&histS[ds[e]], 1);
}

__global__ void scan1_k(const int* __restrict__ hist, int n, int* __restrict__ rowptr,
                        int* __restrict__ part) {
  __shared__ int s[256];
  int t = threadIdx.x;
  int idx = blockIdx.x * 256 + t;
  int v = (idx > 0 && idx < n) ? hist[idx - 1] : 0;
  s[t] = v;
  __syncthreads();
  for (int off = 1; off < 256; off <<= 1) {
    int x = (t >= off) ? s[t - off] : 0;
    __syncthreads();
    s[t] += x;
    __syncthreads();
  }
  if (idx < n) rowptr[idx] = s[t];
  if (t == 255) part[blockIdx.x] = s[255];
}

__global__ void scan2_k(int* __restrict__ part, int nb) {
  __shared__ int s[1024];
  int t = threadIdx.x;
  int v = (t < nb) ? part[t] : 0;
  s[t] = v;
  __syncthreads();
  for (int off = 1; off < 1024; off <<= 1) {
    int x = (t >= off) ? s[t - off] : 0;
    __syncthreads();
    s[t] += x;
    __syncthreads();
  }
  if (t < nb) part[t] = s[t] - v;  // exclusive
}

__global__ void scan3_k(int* __restrict__ rowptr, int n, const int* __restrict__ part) {
  int idx = blockIdx.x * 256 + threadIdx.x;
  if (idx < n) rowptr[idx] += part[blockIdx.x];
}

__global__ void fill_k(const int* __restrict__ su, const int* __restrict__ ds,
                       const int* __restrict__ ss, const int* __restrict__ du,
                       const int* __restrict__ rpU, const int* __restrict__ rpS,
                       int* __restrict__ curU, int* __restrict__ curS,
                       int* __restrict__ csrU, int* __restrict__ csrS) {
  int e = blockIdx.x * blockDim.x + threadIdx.x;
  if (e >= E_N) return;
  int u = du[e];
  int p = atomicAdd(&curU[u], 1);
  csrU[rpU[u] + p] = ss[e];
  int s = ds[e];
  int q = atomicAdd(&curS[s], 1);
  csrS[rpS[s] + q] = su[e];
}

// ===================== prep: tables + weight swizzle =====================
__global__ void build_tbl27_k(const float* __restrict__ age, const float* __restrict__ gen,
                              const float* __restrict__ W1ur, float* __restrict__ tbl27) {
  int j = threadIdx.x;  // 0..127
  float aw[9], gw[3];
  for (int a = 0; a < 9; ++a) {
    float acc = 0.f;
    for (int k = 0; k < 32; ++k) acc += age[a * 32 + k] * W1ur[k * 128 + j];
    aw[a] = acc;
  }
  for (int g = 0; g < 3; ++g) {
    float acc = 0.f;
    for (int k = 0; k < 32; ++k) acc += gen[g * 32 + k] * W1ur[(32 + k) * 128 + j];
    gw[g] = acc;
  }
  for (int t = 0; t < 27; ++t) tbl27[t * 128 + j] = aw[t / 3] + gw[t % 3];
}

__global__ void wswz_k(const float* __restrict__ Wl, const float* __restrict__ Wr,
                       int Km, int wrOff, int K, ushort_t* __restrict__ dst) {
  int idx = blockIdx.x * blockDim.x + threadIdx.x;
  if (idx >= K * 128) return;
  int NKT = K / 16;
  int j = idx & 7, lane = (idx >> 3) & 63, rest = idx >> 9;
  int kt = rest % NKT, ct = rest / NKT;
  int k = kt * 16 + ((lane >> 5) << 3) + j;
  int n = ct * 32 + (lane & 31);
  float v = (k < Km) ? Wl[k * 128 + n] : Wr[(wrOff + k - Km) * 128 + n];
  dst[idx] = f2bf(v);
}

// ===================== layer-1 gather (fused user+seller) =====================
// wave w < NU: aggU[w] = mean of seller feats (f32 64-d) -> bf16
// wave w >= NU: aggS[w-NU] = mean of x_u = [age||gen||xu] (128-d) -> bf16
// 4-way unrolled: 4 independent row-loads in flight per wave (latency fix).
__global__ void gather1_k(const int* __restrict__ rpU, const int* __restrict__ csrU,
                          const float* __restrict__ xs,
                          const int* __restrict__ rpS, const int* __restrict__ csrS,
                          const float* __restrict__ xu, const int* __restrict__ x1,
                          const float* __restrict__ age, const float* __restrict__ gen,
                          ushort_t* __restrict__ aggU, ushort_t* __restrict__ aggS) {
  int w = (blockIdx.x * blockDim.x + threadIdx.x) >> 6;
  int lane = threadIdx.x & 63;
  if (w < NU_N) {
    int b = rpU[w], e = rpU[w + 1], n = e - b;
    float a0 = 0.f, a1 = 0.f, a2 = 0.f, a3 = 0.f;
    for (int base = 0; base < n; base += 4) {
      int i0 = b + base, rem = n - base;
      int j0 = csrU[i0];
      int j1 = csrU[(rem > 1) ? i0 + 1 : i0];
      int j2 = csrU[(rem > 2) ? i0 + 2 : i0];
      int j3 = csrU[(rem > 3) ? i0 + 3 : i0];
      float v0 = xs[(size_t)j0 * 64 + lane];
      float v1 = xs[(size_t)j1 * 64 + lane];
      float v2 = xs[(size_t)j2 * 64 + lane];
      float v3 = xs[(size_t)j3 * 64 + lane];
      a0 += v0;
      a1 += (rem > 1) ? v1 : 0.f;
      a2 += (rem > 2) ? v2 : 0.f;
      a3 += (rem > 3) ? v3 : 0.f;
    }
    float inv = 1.0f / fmaxf((float)n, 1.0f);
    aggU[(size_t)w * 64 + lane] = f2bf(((a0 + a1) + (a2 + a3)) * inv);
  } else if (w < NU_N + NS_N) {
    int row = w - NU_N;
    int b = rpS[row], e = rpS[row + 1], n = e - b;
    const int2* x1p = (const int2*)x1;
    float a0 = 0.f, a1 = 0.f, a2 = 0.f, a3 = 0.f;  // xu part
    float e0 = 0.f, e1 = 0.f, e2 = 0.f, e3 = 0.f;  // emb part
    for (int base = 0; base < n; base += 4) {
      int i0 = b + base, rem = n - base;
      int j0 = csrS[i0];
      int j1 = csrS[(rem > 1) ? i0 + 1 : i0];
      int j2 = csrS[(rem > 2) ? i0 + 2 : i0];
      int j3 = csrS[(rem > 3) ? i0 + 3 : i0];
      int2 q0 = x1p[j0];
      int2 q1 = x1p[j1];
      int2 q2 = x1p[j2];
      int2 q3 = x1p[j3];
      float u0 = xu[(size_t)j0 * 64 + lane];
      float u1 = xu[(size_t)j1 * 64 + lane];
      float u2 = xu[(size_t)j2 * 64 + lane];
      float u3 = xu[(size_t)j3 * 64 + lane];
      float m0 = (lane < 32) ? age[q0.x * 32 + lane] : gen[q0.y * 32 + (lane - 32)];
      float m1 = (lane < 32) ? age[q1.x * 32 + lane] : gen[q1.y * 32 + (lane - 32)];
      float m2 = (lane < 32) ? age[q2.x * 32 + lane] : gen[q2.y * 32 + (lane - 32)];
      float m3 = (lane < 32) ? age[q3.x * 32 + lane] : gen[q3.y * 32 + (lane - 32)];
      a0 += u0;                      e0 += m0;
      a1 += (rem > 1) ? u1 : 0.f;    e1 += (rem > 1) ? m1 : 0.f;
      a2 += (rem > 2) ? u2 : 0.f;    e2 += (rem > 2) ? m2 : 0.f;
      a3 += (rem > 3) ? u3 : 0.f;    e3 += (rem > 3) ? m3 : 0.f;
    }
    float inv = 1.0f / fmaxf((float)n, 1.0f);
    aggS[(size_t)row * 128 + lane]      = f2bf(((e0 + e1) + (e2 + e3)) * inv);
    aggS[(size_t)row * 128 + 64 + lane] = f2bf(((a0 + a1) + (a2 + a3)) * inv);
  }
}

// ===================== layer-2 gather (fused user+seller) =====================
// mean of bf16 128-d rows; lane loads one packed uint (2 bf16).
__global__ void gather2_k(const int* __restrict__ rpU, const int* __restrict__ csrU,
                          const ushort_t* __restrict__ s1,
                          const int* __restrict__ rpS, const int* __restrict__ csrS,
                          const ushort_t* __restrict__ u1,
                          ushort_t* __restrict__ aggU, ushort_t* __restrict__ aggS) {
  int w = (blockIdx.x * blockDim.x + threadIdx.x) >> 6;
  int lane = threadIdx.x & 63;
  const int* rp; const int* csr; const uint_t* src; uint_t* dst; int row;
  if (w < NU_N) {
    rp = rpU; csr = csrU; src = (const uint_t*)s1; dst = (uint_t*)aggU; row = w;
  } else if (w < NU_N + NS_N) {
    rp = rpS; csr = csrS; src = (const uint_t*)u1; dst = (uint_t*)aggS; row = w - NU_N;
  } else return;
  int b = rp[row], e = rp[row + 1], n = e - b;
  float a0 = 0.f, a1 = 0.f, b0 = 0.f, b1 = 0.f;
  float c0 = 0.f, c1 = 0.f, d0 = 0.f, d1 = 0.f;
  for (int base = 0; base < n; base += 4) {
    int i0 = b + base, rem = n - base;
    int j0 = csr[i0];
    int j1 = csr[(rem > 1) ? i0 + 1 : i0];
    int j2 = csr[(rem > 2) ? i0 + 2 : i0];
    int j3 = csr[(rem > 3) ? i0 + 3 : i0];
    uint_t v0 = src[(size_t)j0 * 64 + lane];
    uint_t v1 = src[(size_t)j1 * 64 + lane];
    uint_t v2 = src[(size_t)j2 * 64 + lane];
    uint_t v3 = src[(size_t)j3 * 64 + lane];
    a0 += bf2f(v0 & 0xffffu);                     a1 += bf2f(v0 >> 16);
    b0 += (rem > 1) ? bf2f(v1 & 0xffffu) : 0.f;   b1 += (rem > 1) ? bf2f(v1 >> 16) : 0.f;
    c0 += (rem > 2) ? bf2f(v2 & 0xffffu) : 0.f;   c1 += (rem > 2) ? bf2f(v2 >> 16) : 0.f;
    d0 += (rem > 3) ? bf2f(v3 & 0xffffu) : 0.f;   d1 += (rem > 3) ? bf2f(v3 >> 16) : 0.f;
  }
  float inv = 1.0f / fmaxf((float)n, 1.0f);
  float lo = ((a0 + b0) + (c0 + d0)) * inv;
  float hi = ((a1 + b1) + (c1 + d1)) * inv;
  dst[(size_t)row * 64 + lane] = (uint_t)f2bf(lo) | ((uint_t)f2bf(hi) << 16);
}

// ===================== MFMA row-GEMM =====================
template <int KM, int KS, bool TBL, bool SELF_BF16>
__global__ __launch_bounds__(256, 2) void gemm_mfma_k(
    int nrows, const ushort_t* __restrict__ agg, const void* self,
    const ushort_t* __restrict__ wswz, const float* __restrict__ bias,
    const float* __restrict__ tbl27, const int* __restrict__ x1, ushort_t* out) {
  constexpr int K = KM + KS;
  constexpr int NKT = K / 16;
  __shared__ short sW[K * 128];

  {
    const uint4* g4 = (const uint4*)wswz;
    uint4* s4 = (uint4*)sW;
    for (int i = threadIdx.x; i < K * 16; i += 256) s4[i] = g4[i];
  }
  __syncthreads();

  int wave = threadIdx.x >> 6, lane = threadIdx.x & 63;
  int r0 = blockIdx.x * 256 + wave * 64;
  int qk = (lane >> 5) << 3;  // k sub-offset (0 or 8)

  int ra = r0 + (lane & 31), rb = ra + 32;
  int rac = (ra < nrows) ? ra : 0, rbc = (rb < nrows) ? rb : 0;

  f32x16 acc[2][4];
#pragma unroll
  for (int rt = 0; rt < 2; ++rt)
#pragma unroll
    for (int ct = 0; ct < 4; ++ct) acc[rt][ct] = (f32x16)0.0f;

  const short8* sWv = (const short8*)sW;

#pragma unroll
  for (int kt = 0; kt < NKT; ++kt) {
    int k0 = kt * 16 + qk;
    short8 af, bf;
    if (kt * 16 < KM) {  // compile-time: mean part (KM % 16 == 0)
      af = *((const short8*)(agg + (size_t)rac * KM + k0));
      bf = *((const short8*)(agg + (size_t)rbc * KM + k0));
    } else if (SELF_BF16) {
      const ushort_t* sp = (const ushort_t*)self;
      af = *((const short8*)(sp + (size_t)rac * KS + (k0 - KM)));
      bf = *((const short8*)(sp + (size_t)rbc * KS + (k0 - KM)));
    } else {
      const float* pa = (const float*)self + (size_t)rac * KS + (k0 - KM);
      const float* pb = (const float*)self + (size_t)rbc * KS + (k0 - KM);
      float4 a0 = ((const float4*)pa)[0], a1 = ((const float4*)pa)[1];
      float4 b0 = ((const float4*)pb)[0], b1 = ((const float4*)pb)[1];
      af[0] = f2bf(a0.x); af[1] = f2bf(a0.y); af[2] = f2bf(a0.z); af[3] = f2bf(a0.w);
      af[4] = f2bf(a1.x); af[5] = f2bf(a1.y); af[6] = f2bf(a1.z); af[7] = f2bf(a1.w);
      bf[0] = f2bf(b0.x); bf[1] = f2bf(b0.y); bf[2] = f2bf(b0.z); bf[3] = f2bf(b0.w);
      bf[4] = f2bf(b1.x); bf[5] = f2bf(b1.y); bf[6] = f2bf(b1.z); bf[7] = f2bf(b1.w);
    }
#pragma unroll
    for (int ct = 0; ct < 4; ++ct) {
      short8 wf = sWv[(ct * NKT + kt) * 64 + lane];
      acc[0][ct] = __builtin_amdgcn_mfma_f32_32x32x16_bf16(af, wf, acc[0][ct], 0, 0, 0);
      acc[1][ct] = __builtin_amdgcn_mfma_f32_32x32x16_bf16(bf, wf, acc[1][ct], 0, 0, 0);
    }
  }

  // epilogue: C layout col=lane&31, row=(reg&3)+8*(reg>>2)+4*(lane>>5)
  int nloc = lane & 31;
  float bn[4];
#pragma unroll
  for (int ct = 0; ct < 4; ++ct) bn[ct] = bias[ct * 32 + nloc];
  int rowq = 4 * (lane >> 5);
#pragma unroll
  for (int rt = 0; rt < 2; ++rt) {
#pragma unroll
    for (int reg = 0; reg < 16; ++reg) {
      int row = r0 + rt * 32 + (reg & 3) + 8 * (reg >> 2) + rowq;
      if (row < nrows) {
        const float* tp = nullptr;
        if (TBL) {
          int a = x1[2 * row], g = x1[2 * row + 1];
          tp = tbl27 + (a * 3 + g) * 128 + nloc;
        }
#pragma unroll
        for (int ct = 0; ct < 4; ++ct) {
          float v = acc[rt][ct][reg] + bn[ct];
          if (TBL) v += tp[ct * 32];
          out[(size_t)row * 128 + ct * 32 + nloc] = f2bf(fmaxf(v, 0.0f));
        }
      }
    }
  }
}

// ===================== final =====================
__global__ void final_k(const ushort_t* __restrict__ u2, const ushort_t* __restrict__ s2,
                        const int* __restrict__ mu, const int* __restrict__ ms,
                        const float* __restrict__ lw, const float* __restrict__ lb,
                        float* __restrict__ out) {
  int w = (blockIdx.x * blockDim.x + threadIdx.x) >> 6;
  int lane = threadIdx.x & 63;
  if (w >= M_N) return;
  int iu = mu[w], is = ms[w];
  uint_t a = ((const uint_t*)(u2 + (size_t)iu * 128))[lane];
  uint_t b = ((const uint_t*)(s2 + (size_t)is * 128))[lane];
  float p = bf2f(a & 0xffffu) * lw[2 * lane] + bf2f(a >> 16) * lw[2 * lane + 1]
          + bf2f(b & 0xffffu) * lw[128 + 2 * lane] + bf2f(b >> 16) * lw[129 + 2 * lane];
#pragma unroll
  for (int off = 32; off > 0; off >>= 1) p += __shfl_down(p, off, 64);
  if (lane == 0) out[w] = 1.0f / (1.0f + expf(-(p + lb[0])));
}

extern "C" void kernel_launch(void* const* d_in, const int* in_sizes, int n_in,
                              void* d_out, int out_size, void* d_ws, size_t ws_size,
                              hipStream_t stream) {
  const float* xu   = (const float*)d_in[0];
  const float* xs   = (const float*)d_in[1];
  const int*   x1   = (const int*)d_in[2];
  const int*   su   = (const int*)d_in[3];
  const int*   ds   = (const int*)d_in[4];
  const int*   ss   = (const int*)d_in[5];
  const int*   du   = (const int*)d_in[6];
  const int*   mu   = (const int*)d_in[7];
  const int*   ms   = (const int*)d_in[8];
  const float* age  = (const float*)d_in[9];
  const float* gen  = (const float*)d_in[10];
  const float* W1ul = (const float*)d_in[11];
  const float* W1ur = (const float*)d_in[12];
  const float* b1u  = (const float*)d_in[13];
  const float* W1sl = (const float*)d_in[14];
  const float* W1sr = (const float*)d_in[15];
  const float* b1s  = (const float*)d_in[16];
  const float* W2ul = (const float*)d_in[17];
  const float* W2ur = (const float*)d_in[18];
  const float* b2u  = (const float*)d_in[19];
  const float* W2sl = (const float*)d_in[20];
  const float* W2sr = (const float*)d_in[21];
  const float* b2s  = (const float*)d_in[22];
  const float* lw   = (const float*)d_in[23];
  const float* lb   = (const float*)d_in[24];

  char* w = (char*)d_ws;
  ushort_t* aggU = (ushort_t*)(w + OFF_AGGU);
  ushort_t* aggS = (ushort_t*)(w + OFF_AGGS);
  ushort_t* ub   = (ushort_t*)(w + OFF_U);
  ushort_t* sb   = (ushort_t*)(w + OFF_S);
  float* tbl27   = (float*)(w + OFF_TBL27);
  ushort_t* wz1u = (ushort_t*)(w + OFF_WZ1U);
  ushort_t* wz1s = (ushort_t*)(w + OFF_WZ1S);
  ushort_t* wz2u = (ushort_t*)(w + OFF_WZ2U);
  ushort_t* wz2s = (ushort_t*)(w + OFF_WZ2S);
  int* rpU   = (int*)(w + OFF_RPU);
  int* rpS   = (int*)(w + OFF_RPS);
  int* csrU  = (int*)(w + OFF_CSRU);
  int* csrS  = (int*)(w + OFF_CSRS);
  int* histU = (int*)(w + OFF_HISTU);
  int* histS = (int*)(w + OFF_HISTS);
  int* curU  = (int*)(w + OFF_CURU);
  int* curS  = (int*)(w + OFF_CURS);
  int* part  = (int*)(w + OFF_PART);
  float* out = (float*)d_out;

  const int EB = (E_N + 255) / 256;
  const int NBU = (NU_N + 1 + 255) / 256;
  const int NBS = (NS_N + 1 + 255) / 256;

  // ---- CSR build (once; shared by both layers) ----
  hipMemsetAsync(histU, 0, NU_N * 4, stream);
  hipMemsetAsync(histS, 0, NS_N * 4, stream);
  hipMemsetAsync(curU, 0, NU_N * 4, stream);
  hipMemsetAsync(curS, 0, NS_N * 4, stream);
  hist_k<<<EB, 256, 0, stream>>>(du, ds, histU, histS);
  scan1_k<<<NBU, 256, 0, stream>>>(histU, NU_N + 1, rpU, part);
  scan2_k<<<1, 1024, 0, stream>>>(part, NBU);
  scan3_k<<<NBU, 256, 0, stream>>>(rpU, NU_N + 1, part);
  scan1_k<<<NBS, 256, 0, stream>>>(histS, NS_N + 1, rpS, part);
  scan2_k<<<1, 1024, 0, stream>>>(part, NBS);
  scan3_k<<<NBS, 256, 0, stream>>>(rpS, NS_N + 1, part);
  fill_k<<<EB, 256, 0, stream>>>(su, ds, ss, du, rpU, rpS, curU, curS, csrU, csrS);

  // ---- prep: tables + swizzled bf16 weights ----
  build_tbl27_k<<<1, 128, 0, stream>>>(age, gen, W1ur, tbl27);
  wswz_k<<<(128 * 128 + 255) / 256, 256, 0, stream>>>(W1ul, W1ur, 64, 64, 128, wz1u);
  wswz_k<<<(192 * 128 + 255) / 256, 256, 0, stream>>>(W1sl, W1sr, 128, 0, 192, wz1s);
  wswz_k<<<(256 * 128 + 255) / 256, 256, 0, stream>>>(W2ul, W2ur, 128, 0, 256, wz2u);
  wswz_k<<<(256 * 128 + 255) / 256, 256, 0, stream>>>(W2sl, W2sr, 128, 0, 256, wz2s);

  // ---- layer 1 ----
  gather1_k<<<(NU_N + NS_N) / 4, 256, 0, stream>>>(rpU, csrU, xs, rpS, csrS, xu, x1,
                                                   age, gen, aggU, aggS);
  gemm_mfma_k<64, 64, true, false><<<(NU_N + 255) / 256, 256, 0, stream>>>(
      NU_N, aggU, xu, wz1u, b1u, tbl27, x1, ub);
  gemm_mfma_k<128, 64, false, false><<<(NS_N + 255) / 256, 256, 0, stream>>>(
      NS_N, aggS, xs, wz1s, b1s, nullptr, nullptr, sb);

  // ---- layer 2 ----
  gather2_k<<<(NU_N + NS_N) / 4, 256, 0, stream>>>(rpU, csrU, sb, rpS, csrS, ub,
                                                   aggU, aggS);
  gemm_mfma_k<128, 128, false, true><<<(NU_N + 255) / 256, 256, 0, stream>>>(
      NU_N, aggU, ub, wz2u, b2u, nullptr, nullptr, ub);
  gemm_mfma_k<128, 128, false, true><<<(NS_N + 255) / 256, 256, 0, stream>>>(
      NS_N, aggS, sb, wz2s, b2s, nullptr, nullptr, sb);

  // ---- final linear + sigmoid ----
  final_k<<<(M_N * 64 + 255) / 256, 256, 0, stream>>>(ub, sb, mu, ms, lw, lb, out);
}

// Round 6
// 736.230 us; speedup vs baseline: 5.4256x; 1.0199x over previous
//
#include <hip/hip_runtime.h>
#include <math.h>

#define NU_N 200000
#define NS_N 50000
#define E_N  1000000
#define M_N  100000

typedef __attribute__((ext_vector_type(8))) short short8;
typedef __attribute__((ext_vector_type(16))) float f32x16;
typedef unsigned short ushort_t;
typedef unsigned int uint_t;

// ---- workspace layout (bytes), total ~171 MB ----
static constexpr size_t OFF_AGGU  = 0;            // NU x 128 bf16 = 51,200,000
static constexpr size_t OFF_AGGS  = 51200000;     // NS x 128 bf16 = 12,800,000
static constexpr size_t OFF_U     = 64000000;     // NU x 128 bf16 (u1 then u2 in-place)
static constexpr size_t OFF_S     = 115200000;    // NS x 128 bf16
static constexpr size_t OFF_TBL27 = 128000000;    // 27 x 128 f32
static constexpr size_t OFF_WZ1U  = 128013824;    // K=128 swizzled bf16
static constexpr size_t OFF_WZ1S  = 128046592;    // K=192
static constexpr size_t OFF_WZ2U  = 128095744;    // K=256
static constexpr size_t OFF_WZ2S  = 128161280;    // K=256
static constexpr size_t OFF_RPU   = 128226816;    // (NU+1) int
static constexpr size_t OFF_RPS   = 129026848;    // (NS+1) int
static constexpr size_t OFF_CSRU  = 129226880;    // E int (seller srcs, dst=user)
static constexpr size_t OFF_CSRS  = 133226880;    // E int (user srcs, dst=seller)
static constexpr size_t OFF_HISTU = 137226880;    // NU int
static constexpr size_t OFF_HISTS = 138026880;    // NS int
static constexpr size_t OFF_CURU  = 138226880;    // NU int
static constexpr size_t OFF_CURS  = 139026880;    // NS int
static constexpr size_t OFF_PART  = 139226880;    // 4 KB
static constexpr size_t OFF_XU16  = 139231232;    // NU x 64 bf16 = 25,600,000
static constexpr size_t OFF_XS16  = 164831232;    // NS x 64 bf16 =  6,400,000

__device__ inline ushort_t f2bf(float f) {
  union { float f; uint_t u; } c; c.f = f;
  uint_t r = (c.u + 0x7FFFu + ((c.u >> 16) & 1u)) >> 16;
  return (ushort_t)r;
}
__device__ inline float bf2f(uint_t u) {
  union { uint_t u; float f; } c; c.u = u << 16;
  return c.f;
}
__device__ inline float bfu2f(ushort_t u) { return bf2f((uint_t)u); }

// ===================== f32 -> bf16 conversion (4 elems/thread) =====================
__global__ void cvt_bf16_k(const float* __restrict__ src, ushort_t* __restrict__ dst, int n4) {
  int i = blockIdx.x * blockDim.x + threadIdx.x;
  if (i >= n4) return;
  float4 v = ((const float4*)src)[i];
  uint2 o;
  o.x = (uint_t)f2bf(v.x) | ((uint_t)f2bf(v.y) << 16);
  o.y = (uint_t)f2bf(v.z) | ((uint_t)f2bf(v.w) << 16);
  ((uint2*)dst)[i] = o;
}

// ===================== CSR build =====================
__global__ void hist_k(const int* __restrict__ du, const int* __restrict__ ds,
                       int* __restrict__ histU, int* __restrict__ histS) {
  int e = blockIdx.x * blockDim.x + threadIdx.x;
  if (e >= E_N) return;
  atomicAdd(&histU[du[e]], 1);
  atomicAdd(&histS[ds[e]], 1);
}

__global__ void scan1_k(const int* __restrict__ hist, int n, int* __restrict__ rowptr,
                        int* __restrict__ part) {
  __shared__ int s[256];
  int t = threadIdx.x;
  int idx = blockIdx.x * 256 + t;
  int v = (idx > 0 && idx < n) ? hist[idx - 1] : 0;
  s[t] = v;
  __syncthreads();
  for (int off = 1; off < 256; off <<= 1) {
    int x = (t >= off) ? s[t - off] : 0;
    __syncthreads();
    s[t] += x;
    __syncthreads();
  }
  if (idx < n) rowptr[idx] = s[t];
  if (t == 255) part[blockIdx.x] = s[255];
}

__global__ void scan2_k(int* __restrict__ part, int nb) {
  __shared__ int s[1024];
  int t = threadIdx.x;
  int v = (t < nb) ? part[t] : 0;
  s[t] = v;
  __syncthreads();
  for (int off = 1; off < 1024; off <<= 1) {
    int x = (t >= off) ? s[t - off] : 0;
    __syncthreads();
    s[t] += x;
    __syncthreads();
  }
  if (t < nb) part[t] = s[t] - v;  // exclusive
}

__global__ void scan3_k(int* __restrict__ rowptr, int n, const int* __restrict__ part) {
  int idx = blockIdx.x * 256 + threadIdx.x;
  if (idx < n) rowptr[idx] += part[blockIdx.x];
}

__global__ void fill_k(const int* __restrict__ su, const int* __restrict__ ds,
                       const int* __restrict__ ss, const int* __restrict__ du,
                       const int* __restrict__ rpU, const int* __restrict__ rpS,
                       int* __restrict__ curU, int* __restrict__ curS,
                       int* __restrict__ csrU, int* __restrict__ csrS) {
  int e = blockIdx.x * blockDim.x + threadIdx.x;
  if (e >= E_N) return;
  int u = du[e];
  int p = atomicAdd(&curU[u], 1);
  csrU[rpU[u] + p] = ss[e];
  int s = ds[e];
  int q = atomicAdd(&curS[s], 1);
  csrS[rpS[s] + q] = su[e];
}

// ===================== prep: tables + weight swizzle =====================
__global__ void build_tbl27_k(const float* __restrict__ age, const float* __restrict__ gen,
                              const float* __restrict__ W1ur, float* __restrict__ tbl27) {
  int j = threadIdx.x;  // 0..127
  float aw[9], gw[3];
  for (int a = 0; a < 9; ++a) {
    float acc = 0.f;
    for (int k = 0; k < 32; ++k) acc += age[a * 32 + k] * W1ur[k * 128 + j];
    aw[a] = acc;
  }
  for (int g = 0; g < 3; ++g) {
    float acc = 0.f;
    for (int k = 0; k < 32; ++k) acc += gen[g * 32 + k] * W1ur[(32 + k) * 128 + j];
    gw[g] = acc;
  }
  for (int t = 0; t < 27; ++t) tbl27[t * 128 + j] = aw[t / 3] + gw[t % 3];
}

__global__ void wswz_k(const float* __restrict__ Wl, const float* __restrict__ Wr,
                       int Km, int wrOff, int K, ushort_t* __restrict__ dst) {
  int idx = blockIdx.x * blockDim.x + threadIdx.x;
  if (idx >= K * 128) return;
  int NKT = K / 16;
  int j = idx & 7, lane = (idx >> 3) & 63, rest = idx >> 9;
  int kt = rest % NKT, ct = rest / NKT;
  int k = kt * 16 + ((lane >> 5) << 3) + j;
  int n = ct * 32 + (lane & 31);
  float v = (k < Km) ? Wl[k * 128 + n] : Wr[(wrOff + k - Km) * 128 + n];
  dst[idx] = f2bf(v);
}

// ===================== layer-1 gather (fused, bf16 rows, 8-way unroll) ==========
// wave w < NU: aggU[w] = mean of seller feats (bf16 64-d, lane=ushort)
// wave w >= NU: aggS[w-NU] = mean of [age||gen||xu16] (emb f32 tables, xu bf16)
__global__ void gather1_k(const int* __restrict__ rpU, const int* __restrict__ csrU,
                          const ushort_t* __restrict__ xs16,
                          const int* __restrict__ rpS, const int* __restrict__ csrS,
                          const ushort_t* __restrict__ xu16, const int* __restrict__ x1,
                          const float* __restrict__ age, const float* __restrict__ gen,
                          ushort_t* __restrict__ aggU, ushort_t* __restrict__ aggS) {
  int w = (blockIdx.x * blockDim.x + threadIdx.x) >> 6;
  int lane = threadIdx.x & 63;
  if (w < NU_N) {
    int b = rpU[w], e = rpU[w + 1], n = e - b;
    float acc[8];
#pragma unroll
    for (int k = 0; k < 8; ++k) acc[k] = 0.f;
    for (int base = 0; base < n; base += 8) {
      int i0 = b + base, rem = n - base;
      int idx[8]; ushort_t v[8];
#pragma unroll
      for (int k = 0; k < 8; ++k) idx[k] = csrU[(rem > k) ? i0 + k : i0];
#pragma unroll
      for (int k = 0; k < 8; ++k) v[k] = xs16[(size_t)idx[k] * 64 + lane];
#pragma unroll
      for (int k = 0; k < 8; ++k) acc[k] += (rem > k) ? bfu2f(v[k]) : 0.f;
    }
    float s = ((acc[0] + acc[1]) + (acc[2] + acc[3])) +
              ((acc[4] + acc[5]) + (acc[6] + acc[7]));
    float inv = 1.0f / fmaxf((float)n, 1.0f);
    aggU[(size_t)w * 64 + lane] = f2bf(s * inv);
  } else if (w < NU_N + NS_N) {
    int row = w - NU_N;
    int b = rpS[row], e = rpS[row + 1], n = e - b;
    const int2* x1p = (const int2*)x1;
    float au[8], ae[8];
#pragma unroll
    for (int k = 0; k < 8; ++k) { au[k] = 0.f; ae[k] = 0.f; }
    for (int base = 0; base < n; base += 8) {
      int i0 = b + base, rem = n - base;
      int idx[8]; int2 q[8]; ushort_t u[8]; float m[8];
#pragma unroll
      for (int k = 0; k < 8; ++k) idx[k] = csrS[(rem > k) ? i0 + k : i0];
#pragma unroll
      for (int k = 0; k < 8; ++k) q[k] = x1p[idx[k]];
#pragma unroll
      for (int k = 0; k < 8; ++k) u[k] = xu16[(size_t)idx[k] * 64 + lane];
#pragma unroll
      for (int k = 0; k < 8; ++k)
        m[k] = (lane < 32) ? age[q[k].x * 32 + lane] : gen[q[k].y * 32 + (lane - 32)];
#pragma unroll
      for (int k = 0; k < 8; ++k) {
        au[k] += (rem > k) ? bfu2f(u[k]) : 0.f;
        ae[k] += (rem > k) ? m[k] : 0.f;
      }
    }
    float su_ = ((au[0] + au[1]) + (au[2] + au[3])) +
                ((au[4] + au[5]) + (au[6] + au[7]));
    float se_ = ((ae[0] + ae[1]) + (ae[2] + ae[3])) +
                ((ae[4] + ae[5]) + (ae[6] + ae[7]));
    float inv = 1.0f / fmaxf((float)n, 1.0f);
    aggS[(size_t)row * 128 + lane]      = f2bf(se_ * inv);
    aggS[(size_t)row * 128 + 64 + lane] = f2bf(su_ * inv);
  }
}

// ===================== layer-2 gather (fused, 8-way unroll) =====================
__global__ void gather2_k(const int* __restrict__ rpU, const int* __restrict__ csrU,
                          const ushort_t* __restrict__ s1,
                          const int* __restrict__ rpS, const int* __restrict__ csrS,
                          const ushort_t* __restrict__ u1,
                          ushort_t* __restrict__ aggU, ushort_t* __restrict__ aggS) {
  int w = (blockIdx.x * blockDim.x + threadIdx.x) >> 6;
  int lane = threadIdx.x & 63;
  const int* rp; const int* csr; const uint_t* src; uint_t* dst; int row;
  if (w < NU_N) {
    rp = rpU; csr = csrU; src = (const uint_t*)s1; dst = (uint_t*)aggU; row = w;
  } else if (w < NU_N + NS_N) {
    rp = rpS; csr = csrS; src = (const uint_t*)u1; dst = (uint_t*)aggS; row = w - NU_N;
  } else return;
  int b = rp[row], e = rp[row + 1], n = e - b;
  float lo[8], hi[8];
#pragma unroll
  for (int k = 0; k < 8; ++k) { lo[k] = 0.f; hi[k] = 0.f; }
  for (int base = 0; base < n; base += 8) {
    int i0 = b + base, rem = n - base;
    int idx[8]; uint_t v[8];
#pragma unroll
    for (int k = 0; k < 8; ++k) idx[k] = csr[(rem > k) ? i0 + k : i0];
#pragma unroll
    for (int k = 0; k < 8; ++k) v[k] = src[(size_t)idx[k] * 64 + lane];
#pragma unroll
    for (int k = 0; k < 8; ++k) {
      lo[k] += (rem > k) ? bf2f(v[k] & 0xffffu) : 0.f;
      hi[k] += (rem > k) ? bf2f(v[k] >> 16) : 0.f;
    }
  }
  float slo = ((lo[0] + lo[1]) + (lo[2] + lo[3])) + ((lo[4] + lo[5]) + (lo[6] + lo[7]));
  float shi = ((hi[0] + hi[1]) + (hi[2] + hi[3])) + ((hi[4] + hi[5]) + (hi[6] + hi[7]));
  float inv = 1.0f / fmaxf((float)n, 1.0f);
  dst[(size_t)row * 64 + lane] = (uint_t)f2bf(slo * inv) | ((uint_t)f2bf(shi * inv) << 16);
}

// ===================== MFMA row-GEMM (all-bf16 inputs) =====================
// out[M x 128] = relu( [mean | self] @ Wswz + bias (+ tbl27) ), out bf16.
// block = 4 waves = 256 rows; wave: 2 row-tiles x 4 col-tiles of 32x32x16 MFMA.
// self/out may alias (in-place layer 2).
template <int KM, int KS, bool TBL>
__global__ __launch_bounds__(256, 2) void gemm_mfma_k(
    int nrows, const ushort_t* __restrict__ agg, const ushort_t* self,
    const ushort_t* __restrict__ wswz, const float* __restrict__ bias,
    const float* __restrict__ tbl27, const int* __restrict__ x1, ushort_t* out) {
  constexpr int K = KM + KS;
  constexpr int NKT = K / 16;
  __shared__ short sW[K * 128];

  {
    const uint4* g4 = (const uint4*)wswz;
    uint4* s4 = (uint4*)sW;
    for (int i = threadIdx.x; i < K * 16; i += 256) s4[i] = g4[i];
  }
  __syncthreads();

  int wave = threadIdx.x >> 6, lane = threadIdx.x & 63;
  int r0 = blockIdx.x * 256 + wave * 64;
  int qk = (lane >> 5) << 3;  // k sub-offset (0 or 8)

  int ra = r0 + (lane & 31), rb = ra + 32;
  int rac = (ra < nrows) ? ra : 0, rbc = (rb < nrows) ? rb : 0;

  f32x16 acc[2][4];
#pragma unroll
  for (int rt = 0; rt < 2; ++rt)
#pragma unroll
    for (int ct = 0; ct < 4; ++ct) acc[rt][ct] = (f32x16)0.0f;

  const short8* sWv = (const short8*)sW;

#pragma unroll
  for (int kt = 0; kt < NKT; ++kt) {
    int k0 = kt * 16 + qk;
    short8 af, bf;
    if (kt * 16 < KM) {  // compile-time: mean part (KM % 16 == 0)
      af = *((const short8*)(agg + (size_t)rac * KM + k0));
      bf = *((const short8*)(agg + (size_t)rbc * KM + k0));
    } else {
      af = *((const short8*)(self + (size_t)rac * KS + (k0 - KM)));
      bf = *((const short8*)(self + (size_t)rbc * KS + (k0 - KM)));
    }
#pragma unroll
    for (int ct = 0; ct < 4; ++ct) {
      short8 wf = sWv[(ct * NKT + kt) * 64 + lane];
      acc[0][ct] = __builtin_amdgcn_mfma_f32_32x32x16_bf16(af, wf, acc[0][ct], 0, 0, 0);
      acc[1][ct] = __builtin_amdgcn_mfma_f32_32x32x16_bf16(bf, wf, acc[1][ct], 0, 0, 0);
    }
  }

  // epilogue: C layout col=lane&31, row=(reg&3)+8*(reg>>2)+4*(lane>>5)
  int nloc = lane & 31;
  float bn[4];
#pragma unroll
  for (int ct = 0; ct < 4; ++ct) bn[ct] = bias[ct * 32 + nloc];
  int rowq = 4 * (lane >> 5);
#pragma unroll
  for (int rt = 0; rt < 2; ++rt) {
#pragma unroll
    for (int reg = 0; reg < 16; ++reg) {
      int row = r0 + rt * 32 + (reg & 3) + 8 * (reg >> 2) + rowq;
      if (row < nrows) {
        const float* tp = nullptr;
        if (TBL) {
          int a = x1[2 * row], g = x1[2 * row + 1];
          tp = tbl27 + (a * 3 + g) * 128 + nloc;
        }
#pragma unroll
        for (int ct = 0; ct < 4; ++ct) {
          float v = acc[rt][ct][reg] + bn[ct];
          if (TBL) v += tp[ct * 32];
          out[(size_t)row * 128 + ct * 32 + nloc] = f2bf(fmaxf(v, 0.0f));
        }
      }
    }
  }
}

// ===================== final =====================
__global__ void final_k(const ushort_t* __restrict__ u2, const ushort_t* __restrict__ s2,
                        const int* __restrict__ mu, const int* __restrict__ ms,
                        const float* __restrict__ lw, const float* __restrict__ lb,
                        float* __restrict__ out) {
  int w = (blockIdx.x * blockDim.x + threadIdx.x) >> 6;
  int lane = threadIdx.x & 63;
  if (w >= M_N) return;
  int iu = mu[w], is = ms[w];
  uint_t a = ((const uint_t*)(u2 + (size_t)iu * 128))[lane];
  uint_t b = ((const uint_t*)(s2 + (size_t)is * 128))[lane];
  float p = bf2f(a & 0xffffu) * lw[2 * lane] + bf2f(a >> 16) * lw[2 * lane + 1]
          + bf2f(b & 0xffffu) * lw[128 + 2 * lane] + bf2f(b >> 16) * lw[129 + 2 * lane];
#pragma unroll
  for (int off = 32; off > 0; off >>= 1) p += __shfl_down(p, off, 64);
  if (lane == 0) out[w] = 1.0f / (1.0f + expf(-(p + lb[0])));
}

extern "C" void kernel_launch(void* const* d_in, const int* in_sizes, int n_in,
                              void* d_out, int out_size, void* d_ws, size_t ws_size,
                              hipStream_t stream) {
  const float* xu   = (const float*)d_in[0];
  const float* xs   = (const float*)d_in[1];
  const int*   x1   = (const int*)d_in[2];
  const int*   su   = (const int*)d_in[3];
  const int*   ds   = (const int*)d_in[4];
  const int*   ss   = (const int*)d_in[5];
  const int*   du   = (const int*)d_in[6];
  const int*   mu   = (const int*)d_in[7];
  const int*   ms   = (const int*)d_in[8];
  const float* age  = (const float*)d_in[9];
  const float* gen  = (const float*)d_in[10];
  const float* W1ul = (const float*)d_in[11];
  const float* W1ur = (const float*)d_in[12];
  const float* b1u  = (const float*)d_in[13];
  const float* W1sl = (const float*)d_in[14];
  const float* W1sr = (const float*)d_in[15];
  const float* b1s  = (const float*)d_in[16];
  const float* W2ul = (const float*)d_in[17];
  const float* W2ur = (const float*)d_in[18];
  const float* b2u  = (const float*)d_in[19];
  const float* W2sl = (const float*)d_in[20];
  const float* W2sr = (const float*)d_in[21];
  const float* b2s  = (const float*)d_in[22];
  const float* lw   = (const float*)d_in[23];
  const float* lb   = (const float*)d_in[24];

  char* w = (char*)d_ws;
  ushort_t* aggU = (ushort_t*)(w + OFF_AGGU);
  ushort_t* aggS = (ushort_t*)(w + OFF_AGGS);
  ushort_t* ub   = (ushort_t*)(w + OFF_U);
  ushort_t* sb   = (ushort_t*)(w + OFF_S);
  float* tbl27   = (float*)(w + OFF_TBL27);
  ushort_t* wz1u = (ushort_t*)(w + OFF_WZ1U);
  ushort_t* wz1s = (ushort_t*)(w + OFF_WZ1S);
  ushort_t* wz2u = (ushort_t*)(w + OFF_WZ2U);
  ushort_t* wz2s = (ushort_t*)(w + OFF_WZ2S);
  int* rpU   = (int*)(w + OFF_RPU);
  int* rpS   = (int*)(w + OFF_RPS);
  int* csrU  = (int*)(w + OFF_CSRU);
  int* csrS  = (int*)(w + OFF_CSRS);
  int* histU = (int*)(w + OFF_HISTU);
  int* histS = (int*)(w + OFF_HISTS);
  int* curU  = (int*)(w + OFF_CURU);
  int* curS  = (int*)(w + OFF_CURS);
  int* part  = (int*)(w + OFF_PART);
  ushort_t* xu16 = (ushort_t*)(w + OFF_XU16);
  ushort_t* xs16 = (ushort_t*)(w + OFF_XS16);
  float* out = (float*)d_out;

  const int EB = (E_N + 255) / 256;
  const int NBU = (NU_N + 1 + 255) / 256;
  const int NBS = (NS_N + 1 + 255) / 256;

  // ---- CSR build (once; shared by both layers) ----
  hipMemsetAsync(histU, 0, NU_N * 4, stream);
  hipMemsetAsync(histS, 0, NS_N * 4, stream);
  hipMemsetAsync(curU, 0, NU_N * 4, stream);
  hipMemsetAsync(curS, 0, NS_N * 4, stream);
  hist_k<<<EB, 256, 0, stream>>>(du, ds, histU, histS);
  scan1_k<<<NBU, 256, 0, stream>>>(histU, NU_N + 1, rpU, part);
  scan2_k<<<1, 1024, 0, stream>>>(part, NBU);
  scan3_k<<<NBU, 256, 0, stream>>>(rpU, NU_N + 1, part);
  scan1_k<<<NBS, 256, 0, stream>>>(histS, NS_N + 1, rpS, part);
  scan2_k<<<1, 1024, 0, stream>>>(part, NBS);
  scan3_k<<<NBS, 256, 0, stream>>>(rpS, NS_N + 1, part);
  fill_k<<<EB, 256, 0, stream>>>(su, ds, ss, du, rpU, rpS, curU, curS, csrU, csrS);

  // ---- prep: bf16 features + tables + swizzled weights ----
  cvt_bf16_k<<<(NU_N * 16 + 255) / 256, 256, 0, stream>>>(xu, xu16, NU_N * 16);
  cvt_bf16_k<<<(NS_N * 16 + 255) / 256, 256, 0, stream>>>(xs, xs16, NS_N * 16);
  build_tbl27_k<<<1, 128, 0, stream>>>(age, gen, W1ur, tbl27);
  wswz_k<<<(128 * 128 + 255) / 256, 256, 0, stream>>>(W1ul, W1ur, 64, 64, 128, wz1u);
  wswz_k<<<(192 * 128 + 255) / 256, 256, 0, stream>>>(W1sl, W1sr, 128, 0, 192, wz1s);
  wswz_k<<<(256 * 128 + 255) / 256, 256, 0, stream>>>(W2ul, W2ur, 128, 0, 256, wz2u);
  wswz_k<<<(256 * 128 + 255) / 256, 256, 0, stream>>>(W2sl, W2sr, 128, 0, 256, wz2s);

  // ---- layer 1 ----
  gather1_k<<<(NU_N + NS_N) / 4, 256, 0, stream>>>(rpU, csrU, xs16, rpS, csrS, xu16,
                                                   x1, age, gen, aggU, aggS);
  gemm_mfma_k<64, 64, true><<<(NU_N + 255) / 256, 256, 0, stream>>>(
      NU_N, aggU, xu16, wz1u, b1u, tbl27, x1, ub);
  gemm_mfma_k<128, 64, false><<<(NS_N + 255) / 256, 256, 0, stream>>>(
      NS_N, aggS, xs16, wz1s, b1s, nullptr, nullptr, sb);

  // ---- layer 2 ----
  gather2_k<<<(NU_N + NS_N) / 4, 256, 0, stream>>>(rpU, csrU, sb, rpS, csrS, ub,
                                                   aggU, aggS);
  gemm_mfma_k<128, 128, false><<<(NU_N + 255) / 256, 256, 0, stream>>>(
      NU_N, aggU, ub, wz2u, b2u, nullptr, nullptr, ub);
  gemm_mfma_k<128, 128, false><<<(NS_N + 255) / 256, 256, 0, stream>>>(
      NS_N, aggS, sb, wz2s, b2s, nullptr, nullptr, sb);

  // ---- final linear + sigmoid ----
  final_k<<<(M_N * 64 + 255) / 256, 256, 0, stream>>>(ub, sb, mu, ms, lw, lb, out);
}

// Round 8
// 702.147 us; speedup vs baseline: 5.6890x; 1.0485x over previous
//
#include <hip/hip_runtime.h>
#include <math.h>

#define NU_N 200000
#define NS_N 50000
#define E_N  1000000
#define M_N  100000
#define NBU 782   // ceil((NU+1)/256)
#define NBS 196   // ceil((NS+1)/256)

typedef __attribute__((ext_vector_type(8))) short short8;
typedef __attribute__((ext_vector_type(16))) float f32x16;
typedef unsigned short ushort_t;
typedef unsigned int uint_t;

// ---- workspace layout (bytes), ~197 MB ----
static constexpr size_t OFF_AGGU  = 0;             // NU x 128 bf16
static constexpr size_t OFF_AGGS  = 51200000;      // NS x 128 bf16
static constexpr size_t OFF_U     = 64000000;      // (NU+1) x 128 bf16 (u1/u2 + zero pad row)
static constexpr size_t OFF_S     = 115200512;     // (NS+1) x 128 bf16
static constexpr size_t OFF_XCAT  = 128001024;     // (NU+1) x 128 bf16 = [age||gen||xu]
static constexpr size_t OFF_XS16  = 179201536;     // (NS+1) x 64 bf16
static constexpr size_t OFF_TBL27 = 185601792;     // 27 x 128 f32
static constexpr size_t OFF_WZ1U  = 185615616;     // K=128 swizzled bf16
static constexpr size_t OFF_WZ1S  = 185648384;     // K=192
static constexpr size_t OFF_WZ2U  = 185697536;     // K=256
static constexpr size_t OFF_WZ2S  = 185763072;     // K=256
static constexpr size_t OFF_RPU   = 185828608;     // (NU+1) int
static constexpr size_t OFF_RPS   = 186628864;     // (NS+1) int
static constexpr size_t OFF_CSRU  = 186829056;     // E int (seller srcs, dst=user)
static constexpr size_t OFF_CSRS  = 190829056;     // E int (user srcs, dst=seller)
static constexpr size_t OFF_HIST  = 194829056;     // histU|histS|curU|curS = 2,000,000 B
static constexpr size_t OFF_PART  = 196829056;     // 2 x 1024 int

__device__ inline ushort_t f2bf(float f) {
  union { float f; uint_t u; } c; c.f = f;
  uint_t r = (c.u + 0x7FFFu + ((c.u >> 16) & 1u)) >> 16;
  return (ushort_t)r;
}
__device__ inline float u2f(uint_t u) {
  union { uint_t u; float f; } c; c.u = u;
  return c.f;
}
__device__ inline float bf2f(uint_t u) { return u2f(u << 16); }

// ===================== CSR build =====================
__global__ void hist_k(const int* __restrict__ du, const int* __restrict__ ds,
                       int* __restrict__ histU, int* __restrict__ histS) {
  int e = blockIdx.x * blockDim.x + threadIdx.x;
  if (e >= E_N) return;
  atomicAdd(&histU[du[e]], 1);
  atomicAdd(&histS[ds[e]], 1);
}

// merged U+S: blocks [0,NBU) -> U, [NBU,NBU+NBS) -> S
__global__ void scan1_k(const int* __restrict__ histU, const int* __restrict__ histS,
                        int* __restrict__ rpU, int* __restrict__ rpS,
                        int* __restrict__ part) {
  __shared__ int s[256];
  int blk = blockIdx.x;
  const int* hist; int n; int* rowptr; int* pp;
  if (blk < NBU) { hist = histU; n = NU_N + 1; rowptr = rpU; pp = part; }
  else { blk -= NBU; hist = histS; n = NS_N + 1; rowptr = rpS; pp = part + 1024; }
  int t = threadIdx.x;
  int idx = blk * 256 + t;
  int v = (idx > 0 && idx < n) ? hist[idx - 1] : 0;
  s[t] = v;
  __syncthreads();
  for (int off = 1; off < 256; off <<= 1) {
    int x = (t >= off) ? s[t - off] : 0;
    __syncthreads();
    s[t] += x;
    __syncthreads();
  }
  if (idx < n) rowptr[idx] = s[t];
  if (t == 255) pp[blk] = s[255];
}

__global__ void scan2_k(int* __restrict__ part) {
  __shared__ int s[1024];
  int* pp = part + blockIdx.x * 1024;
  int nb = (blockIdx.x == 0) ? NBU : NBS;
  int t = threadIdx.x;
  int v = (t < nb) ? pp[t] : 0;
  s[t] = v;
  __syncthreads();
  for (int off = 1; off < 1024; off <<= 1) {
    int x = (t >= off) ? s[t - off] : 0;
    __syncthreads();
    s[t] += x;
    __syncthreads();
  }
  if (t < nb) pp[t] = s[t] - v;  // exclusive
}

__global__ void scan3_k(int* __restrict__ rpU, int* __restrict__ rpS,
                        const int* __restrict__ part) {
  int blk = blockIdx.x;
  int* rowptr; int n; const int* pp;
  if (blk < NBU) { rowptr = rpU; n = NU_N + 1; pp = part; }
  else { blk -= NBU; rowptr = rpS; n = NS_N + 1; pp = part + 1024; }
  int idx = blk * 256 + threadIdx.x;
  if (idx < n) rowptr[idx] += pp[blk];
}

__global__ void fill_k(const int* __restrict__ su, const int* __restrict__ ds,
                       const int* __restrict__ ss, const int* __restrict__ du,
                       const int* __restrict__ rpU, const int* __restrict__ rpS,
                       int* __restrict__ curU, int* __restrict__ curS,
                       int* __restrict__ csrU, int* __restrict__ csrS) {
  int e = blockIdx.x * blockDim.x + threadIdx.x;
  if (e >= E_N) return;
  int u = du[e];
  int p = atomicAdd(&curU[u], 1);
  csrU[rpU[u] + p] = ss[e];
  int s = ds[e];
  int q = atomicAdd(&curS[s], 1);
  csrS[rpS[s] + q] = su[e];
}

// ===================== prep: xcat/xs16 (bf16) + zero pad rows =====================
// xcat[u] = [age_emb[a] || gen_emb[g] || xu[u]] as bf16; thread = one uint2 (4 bf16)
__global__ void prep_k(const float* __restrict__ xu, const float* __restrict__ xs,
                       const int* __restrict__ x1, const float* __restrict__ age,
                       const float* __restrict__ gen,
                       ushort_t* __restrict__ xcat, ushort_t* __restrict__ xs16,
                       ushort_t* __restrict__ ub, ushort_t* __restrict__ sb) {
  int t = blockIdx.x * 256 + threadIdx.x;
  if (t < NU_N * 32) {
    int u = t >> 5, c2 = t & 31;
    float4 v;
    if (c2 < 16) {
      int2 q = ((const int2*)x1)[u];
      v = (c2 < 8) ? ((const float4*)(age + q.x * 32))[c2]
                   : ((const float4*)(gen + q.y * 32))[c2 - 8];
    } else {
      v = ((const float4*)(xu + (size_t)u * 64))[c2 - 16];
    }
    uint2 o;
    o.x = (uint_t)f2bf(v.x) | ((uint_t)f2bf(v.y) << 16);
    o.y = (uint_t)f2bf(v.z) | ((uint_t)f2bf(v.w) << 16);
    ((uint2*)xcat)[t] = o;
  } else if (t < NU_N * 32 + NS_N * 16) {
    int i = t - NU_N * 32;
    float4 v = ((const float4*)xs)[i];
    uint2 o;
    o.x = (uint_t)f2bf(v.x) | ((uint_t)f2bf(v.y) << 16);
    o.y = (uint_t)f2bf(v.z) | ((uint_t)f2bf(v.w) << 16);
    ((uint2*)xs16)[i] = o;
  } else {
    int t3 = t - NU_N * 32 - NS_N * 16;
    uint2 z; z.x = 0u; z.y = 0u;
    if (t3 < 32)       ((uint2*)xcat)[NU_N * 32 + t3] = z;
    else if (t3 < 48)  ((uint2*)xs16)[NS_N * 16 + (t3 - 32)] = z;
    else if (t3 < 80)  ((uint2*)ub)[NU_N * 32 + (t3 - 48)] = z;
    else if (t3 < 112) ((uint2*)sb)[NS_N * 32 + (t3 - 80)] = z;
  }
}

// ===================== tbl27 + merged weight swizzle =====================
__global__ void build_tbl27_k(const float* __restrict__ age, const float* __restrict__ gen,
                              const float* __restrict__ W1ur, float* __restrict__ tbl27) {
  int j = threadIdx.x;  // 0..127
  float aw[9], gw[3];
  for (int a = 0; a < 9; ++a) {
    float acc = 0.f;
    for (int k = 0; k < 32; ++k) acc += age[a * 32 + k] * W1ur[k * 128 + j];
    aw[a] = acc;
  }
  for (int g = 0; g < 3; ++g) {
    float acc = 0.f;
    for (int k = 0; k < 32; ++k) acc += gen[g * 32 + k] * W1ur[(32 + k) * 128 + j];
    gw[g] = acc;
  }
  for (int t = 0; t < 27; ++t) tbl27[t * 128 + j] = aw[t / 3] + gw[t % 3];
}

// dst[((ct*NKT+kt)*64 + lane)*8 + j] = bf16(Wcat[kt*16+(lane>>5)*8+j][ct*32+(lane&31)])
__global__ void wswz_all_k(const float* __restrict__ W1ul, const float* __restrict__ W1ur,
                           const float* __restrict__ W1sl, const float* __restrict__ W1sr,
                           const float* __restrict__ W2ul, const float* __restrict__ W2ur,
                           const float* __restrict__ W2sl, const float* __restrict__ W2sr,
                           ushort_t* __restrict__ z1u, ushort_t* __restrict__ z1s,
                           ushort_t* __restrict__ z2u, ushort_t* __restrict__ z2s) {
  int idx = blockIdx.x * 256 + threadIdx.x;
  const float *Wl, *Wr; int Km, wrOff, K, i; ushort_t* dst;
  if (idx < 16384)       { Wl = W1ul; Wr = W1ur; Km = 64;  wrOff = 64; K = 128; dst = z1u; i = idx; }
  else if (idx < 40960)  { Wl = W1sl; Wr = W1sr; Km = 128; wrOff = 0;  K = 192; dst = z1s; i = idx - 16384; }
  else if (idx < 73728)  { Wl = W2ul; Wr = W2ur; Km = 128; wrOff = 0;  K = 256; dst = z2u; i = idx - 40960; }
  else if (idx < 106496) { Wl = W2sl; Wr = W2sr; Km = 128; wrOff = 0;  K = 256; dst = z2s; i = idx - 73728; }
  else return;
  int NKT = K / 16;
  int j = i & 7, lane = (i >> 3) & 63, rest = i >> 9;
  int kt = rest % NKT, ct = rest / NKT;
  int k = kt * 16 + ((lane >> 5) << 3) + j;
  int n = ct * 32 + (lane & 31);
  float v = (k < Km) ? Wl[k * 128 + n] : Wr[(wrOff + k - Km) * 128 + n];
  dst[i] = f2bf(v);
}

// ===================== gather cores =====================
// 128-bf16 rows (256 B = 16 uint4): 4 neighbor groups x 16 lanes, dwordx4/lane,
// 8 rows in flight per wave.
__device__ inline void gmean128(int b, int e, const int* __restrict__ csr, int zrow,
                                const ushort_t* __restrict__ src,
                                ushort_t* __restrict__ dst, int lane) {
  int n = e - b;
  int g = lane >> 4, c = lane & 15;
  const uint4* s4 = (const uint4*)src;
  float acc[8];
#pragma unroll
  for (int k = 0; k < 8; ++k) acc[k] = 0.f;
  for (int base = 0; base < n; base += 8) {
    int p0 = b + base + g, p1 = p0 + 4;
    int j0 = csr[min(p0, e - 1)];
    int j1 = csr[min(p1, e - 1)];
    j0 = (p0 < e) ? j0 : zrow;
    j1 = (p1 < e) ? j1 : zrow;
    uint4 v0 = s4[j0 * 16 + c];   // row stride = 16 uint4 (256 B)
    uint4 v1 = s4[j1 * 16 + c];
    acc[0] += bf2f(v0.x); acc[1] += u2f(v0.x & 0xffff0000u);
    acc[2] += bf2f(v0.y); acc[3] += u2f(v0.y & 0xffff0000u);
    acc[4] += bf2f(v0.z); acc[5] += u2f(v0.z & 0xffff0000u);
    acc[6] += bf2f(v0.w); acc[7] += u2f(v0.w & 0xffff0000u);
    acc[0] += bf2f(v1.x); acc[1] += u2f(v1.x & 0xffff0000u);
    acc[2] += bf2f(v1.y); acc[3] += u2f(v1.y & 0xffff0000u);
    acc[4] += bf2f(v1.z); acc[5] += u2f(v1.z & 0xffff0000u);
    acc[6] += bf2f(v1.w); acc[7] += u2f(v1.w & 0xffff0000u);
  }
#pragma unroll
  for (int k = 0; k < 8; ++k) acc[k] += __shfl_down(acc[k], 32);
#pragma unroll
  for (int k = 0; k < 8; ++k) acc[k] += __shfl_down(acc[k], 16);
  if (lane < 16) {
    float inv = 1.0f / fmaxf((float)n, 1.0f);
    uint4 o;
    o.x = (uint_t)f2bf(acc[0] * inv) | ((uint_t)f2bf(acc[1] * inv) << 16);
    o.y = (uint_t)f2bf(acc[2] * inv) | ((uint_t)f2bf(acc[3] * inv) << 16);
    o.z = (uint_t)f2bf(acc[4] * inv) | ((uint_t)f2bf(acc[5] * inv) << 16);
    o.w = (uint_t)f2bf(acc[6] * inv) | ((uint_t)f2bf(acc[7] * inv) << 16);
    ((uint4*)dst)[lane] = o;
  }
}

// 64-bf16 rows (128 B = 8 uint4): 8 neighbor groups x 8 lanes, dwordx4/lane.
__device__ inline void gmean64(int b, int e, const int* __restrict__ csr, int zrow,
                               const ushort_t* __restrict__ src,
                               ushort_t* __restrict__ dst, int lane) {
  int n = e - b;
  int g = lane >> 3, c = lane & 7;
  const uint4* s4 = (const uint4*)src;
  float acc[8];
#pragma unroll
  for (int k = 0; k < 8; ++k) acc[k] = 0.f;
  for (int base = 0; base < n; base += 8) {
    int p = b + base + g;
    int j = csr[min(p, e - 1)];
    j = (p < e) ? j : zrow;
    uint4 v = s4[j * 8 + c];
    acc[0] += bf2f(v.x); acc[1] += u2f(v.x & 0xffff0000u);
    acc[2] += bf2f(v.y); acc[3] += u2f(v.y & 0xffff0000u);
    acc[4] += bf2f(v.z); acc[5] += u2f(v.z & 0xffff0000u);
    acc[6] += bf2f(v.w); acc[7] += u2f(v.w & 0xffff0000u);
  }
#pragma unroll
  for (int k = 0; k < 8; ++k) acc[k] += __shfl_down(acc[k], 32);
#pragma unroll
  for (int k = 0; k < 8; ++k) acc[k] += __shfl_down(acc[k], 16);
#pragma unroll
  for (int k = 0; k < 8; ++k) acc[k] += __shfl_down(acc[k], 8);
  if (lane < 8) {
    float inv = 1.0f / fmaxf((float)n, 1.0f);
    uint4 o;
    o.x = (uint_t)f2bf(acc[0] * inv) | ((uint_t)f2bf(acc[1] * inv) << 16);
    o.y = (uint_t)f2bf(acc[2] * inv) | ((uint_t)f2bf(acc[3] * inv) << 16);
    o.z = (uint_t)f2bf(acc[4] * inv) | ((uint_t)f2bf(acc[5] * inv) << 16);
    o.w = (uint_t)f2bf(acc[6] * inv) | ((uint_t)f2bf(acc[7] * inv) << 16);
    ((uint4*)dst)[lane] = o;
  }
}

// layer 1: users gather xs16 rows (64-d); sellers gather xcat rows (128-d)
__global__ void gather1_k(const int* __restrict__ rpU, const int* __restrict__ csrU,
                          const ushort_t* __restrict__ xs16,
                          const int* __restrict__ rpS, const int* __restrict__ csrS,
                          const ushort_t* __restrict__ xcat,
                          ushort_t* __restrict__ aggU, ushort_t* __restrict__ aggS) {
  int w = (blockIdx.x * blockDim.x + threadIdx.x) >> 6;
  int lane = threadIdx.x & 63;
  if (w < NU_N) {
    gmean64(rpU[w], rpU[w + 1], csrU, NS_N, xs16, aggU + (size_t)w * 64, lane);
  } else if (w < NU_N + NS_N) {
    int r = w - NU_N;
    gmean128(rpS[r], rpS[r + 1], csrS, NU_N, xcat, aggS + (size_t)r * 128, lane);
  }
}

// layer 2: users gather s1 rows; sellers gather u1 rows (both 128-d)
__global__ void gather2_k(const int* __restrict__ rpU, const int* __restrict__ csrU,
                          const ushort_t* __restrict__ s1,
                          const int* __restrict__ rpS, const int* __restrict__ csrS,
                          const ushort_t* __restrict__ u1,
                          ushort_t* __restrict__ aggU, ushort_t* __restrict__ aggS) {
  int w = (blockIdx.x * blockDim.x + threadIdx.x) >> 6;
  int lane = threadIdx.x & 63;
  if (w < NU_N) {
    gmean128(rpU[w], rpU[w + 1], csrU, NS_N, s1, aggU + (size_t)w * 128, lane);
  } else if (w < NU_N + NS_N) {
    int r = w - NU_N;
    gmean128(rpS[r], rpS[r + 1], csrS, NU_N, u1, aggS + (size_t)r * 128, lane);
  }
}

// ===================== MFMA row-GEMM (bf16 in, bf16 out) =====================
// out[nrows x 128] = relu([mean | self] @ Wswz + bias (+ tbl27))
// self stride = SSTR (xcat-strided for layer-1 user). In-place safe for layer 2.
template <int KM, int KS, int SSTR, bool TBL>
__global__ __launch_bounds__(256, 2) void gemm_mfma_k(
    int nrows, const ushort_t* __restrict__ agg, const ushort_t* self,
    const ushort_t* __restrict__ wswz, const float* __restrict__ bias,
    const float* __restrict__ tbl27, const int* __restrict__ x1, ushort_t* out) {
  constexpr int K = KM + KS;
  constexpr int NKT = K / 16;
  __shared__ short sW[K * 128];

  {
    const uint4* g4 = (const uint4*)wswz;
    uint4* s4 = (uint4*)sW;
    for (int i = threadIdx.x; i < K * 16; i += 256) s4[i] = g4[i];
  }
  __syncthreads();

  int wave = threadIdx.x >> 6, lane = threadIdx.x & 63;
  int r0 = blockIdx.x * 256 + wave * 64;
  int qk = (lane >> 5) << 3;  // k sub-offset (0 or 8)

  int ra = r0 + (lane & 31), rb = ra + 32;
  int rac = (ra < nrows) ? ra : 0, rbc = (rb < nrows) ? rb : 0;

  f32x16 acc[2][4];
#pragma unroll
  for (int rt = 0; rt < 2; ++rt)
#pragma unroll
    for (int ct = 0; ct < 4; ++ct) acc[rt][ct] = (f32x16)0.0f;

  const short8* sWv = (const short8*)sW;

#pragma unroll
  for (int kt = 0; kt < NKT; ++kt) {
    int k0 = kt * 16 + qk;
    short8 af, bf;
    if (kt * 16 < KM) {  // compile-time: mean part (KM % 16 == 0)
      af = *((const short8*)(agg + (size_t)rac * KM + k0));
      bf = *((const short8*)(agg + (size_t)rbc * KM + k0));
    } else {
      af = *((const short8*)(self + (size_t)rac * SSTR + (k0 - KM)));
      bf = *((const short8*)(self + (size_t)rbc * SSTR + (k0 - KM)));
    }
#pragma unroll
    for (int ct = 0; ct < 4; ++ct) {
      short8 wf = sWv[(ct * NKT + kt) * 64 + lane];
      acc[0][ct] = __builtin_amdgcn_mfma_f32_32x32x16_bf16(af, wf, acc[0][ct], 0, 0, 0);
      acc[1][ct] = __builtin_amdgcn_mfma_f32_32x32x16_bf16(bf, wf, acc[1][ct], 0, 0, 0);
    }
  }

  // epilogue: C layout col=lane&31, row=(reg&3)+8*(reg>>2)+4*(lane>>5)
  int nloc = lane & 31;
  float bn[4];
#pragma unroll
  for (int ct = 0; ct < 4; ++ct) bn[ct] = bias[ct * 32 + nloc];
  int rowq = 4 * (lane >> 5);
#pragma unroll
  for (int rt = 0; rt < 2; ++rt) {
#pragma unroll
    for (int reg = 0; reg < 16; ++reg) {
      int row = r0 + rt * 32 + (reg & 3) + 8 * (reg >> 2) + rowq;
      if (row < nrows) {
        const float* tp = nullptr;
        if (TBL) {
          int a = x1[2 * row], g = x1[2 * row + 1];
          tp = tbl27 + (a * 3 + g) * 128 + nloc;
        }
#pragma unroll
        for (int ct = 0; ct < 4; ++ct) {
          float v = acc[rt][ct][reg] + bn[ct];
          if (TBL) v += tp[ct * 32];
          out[(size_t)row * 128 + ct * 32 + nloc] = f2bf(fmaxf(v, 0.0f));
        }
      }
    }
  }
}

// ===================== final =====================
__global__ void final_k(const ushort_t* __restrict__ u2, const ushort_t* __restrict__ s2,
                        const int* __restrict__ mu, const int* __restrict__ ms,
                        const float* __restrict__ lw, const float* __restrict__ lb,
                        float* __restrict__ out) {
  int w = (blockIdx.x * blockDim.x + threadIdx.x) >> 6;
  int lane = threadIdx.x & 63;
  if (w >= M_N) return;
  int iu = mu[w], is = ms[w];
  uint_t a = ((const uint_t*)(u2 + (size_t)iu * 128))[lane];
  uint_t b = ((const uint_t*)(s2 + (size_t)is * 128))[lane];
  float p = bf2f(a & 0xffffu) * lw[2 * lane] + bf2f(a >> 16) * lw[2 * lane + 1]
          + bf2f(b & 0xffffu) * lw[128 + 2 * lane] + bf2f(b >> 16) * lw[129 + 2 * lane];
#pragma unroll
  for (int off = 32; off > 0; off >>= 1) p += __shfl_down(p, off, 64);
  if (lane == 0) out[w] = 1.0f / (1.0f + expf(-(p + lb[0])));
}

extern "C" void kernel_launch(void* const* d_in, const int* in_sizes, int n_in,
                              void* d_out, int out_size, void* d_ws, size_t ws_size,
                              hipStream_t stream) {
  const float* xu   = (const float*)d_in[0];
  const float* xs   = (const float*)d_in[1];
  const int*   x1   = (const int*)d_in[2];
  const int*   su   = (const int*)d_in[3];
  const int*   ds   = (const int*)d_in[4];
  const int*   ss   = (const int*)d_in[5];
  const int*   du   = (const int*)d_in[6];
  const int*   mu   = (const int*)d_in[7];
  const int*   ms   = (const int*)d_in[8];
  const float* age  = (const float*)d_in[9];
  const float* gen  = (const float*)d_in[10];
  const float* W1ul = (const float*)d_in[11];
  const float* W1ur = (const float*)d_in[12];
  const float* b1u  = (const float*)d_in[13];
  const float* W1sl = (const float*)d_in[14];
  const float* W1sr = (const float*)d_in[15];
  const float* b1s  = (const float*)d_in[16];
  const float* W2ul = (const float*)d_in[17];
  const float* W2ur = (const float*)d_in[18];
  const float* b2u  = (const float*)d_in[19];
  const float* W2sl = (const float*)d_in[20];
  const float* W2sr = (const float*)d_in[21];
  const float* b2s  = (const float*)d_in[22];
  const float* lw   = (const float*)d_in[23];
  const float* lb   = (const float*)d_in[24];

  char* w = (char*)d_ws;
  ushort_t* aggU = (ushort_t*)(w + OFF_AGGU);
  ushort_t* aggS = (ushort_t*)(w + OFF_AGGS);
  ushort_t* ub   = (ushort_t*)(w + OFF_U);
  ushort_t* sb   = (ushort_t*)(w + OFF_S);
  ushort_t* xcat = (ushort_t*)(w + OFF_XCAT);
  ushort_t* xs16 = (ushort_t*)(w + OFF_XS16);
  float* tbl27   = (float*)(w + OFF_TBL27);
  ushort_t* wz1u = (ushort_t*)(w + OFF_WZ1U);
  ushort_t* wz1s = (ushort_t*)(w + OFF_WZ1S);
  ushort_t* wz2u = (ushort_t*)(w + OFF_WZ2U);
  ushort_t* wz2s = (ushort_t*)(w + OFF_WZ2S);
  int* rpU   = (int*)(w + OFF_RPU);
  int* rpS   = (int*)(w + OFF_RPS);
  int* csrU  = (int*)(w + OFF_CSRU);
  int* csrS  = (int*)(w + OFF_CSRS);
  int* histU = (int*)(w + OFF_HIST);
  int* histS = (int*)(w + OFF_HIST + 800000);
  int* curU  = (int*)(w + OFF_HIST + 1000000);
  int* curS  = (int*)(w + OFF_HIST + 1800000);
  int* part  = (int*)(w + OFF_PART);
  float* out = (float*)d_out;

  const int EB = (E_N + 255) / 256;

  // ---- CSR build (once; shared by both layers) ----
  hipMemsetAsync(w + OFF_HIST, 0, 2000000, stream);  // histU|histS|curU|curS
  hist_k<<<EB, 256, 0, stream>>>(du, ds, histU, histS);
  scan1_k<<<NBU + NBS, 256, 0, stream>>>(histU, histS, rpU, rpS, part);
  scan2_k<<<2, 1024, 0, stream>>>(part);
  scan3_k<<<NBU + NBS, 256, 0, stream>>>(rpU, rpS, part);
  fill_k<<<EB, 256, 0, stream>>>(su, ds, ss, du, rpU, rpS, curU, curS, csrU, csrS);

  // ---- prep: bf16 features (+pads) + tables + swizzled weights ----
  prep_k<<<(NU_N * 32 + NS_N * 16 + 112 + 255) / 256, 256, 0, stream>>>(
      xu, xs, x1, age, gen, xcat, xs16, ub, sb);
  build_tbl27_k<<<1, 128, 0, stream>>>(age, gen, W1ur, tbl27);
  wswz_all_k<<<416, 256, 0, stream>>>(W1ul, W1ur, W1sl, W1sr, W2ul, W2ur, W2sl, W2sr,
                                      wz1u, wz1s, wz2u, wz2s);

  // ---- layer 1 ----
  gather1_k<<<(NU_N + NS_N) / 4, 256, 0, stream>>>(rpU, csrU, xs16, rpS, csrS, xcat,
                                                   aggU, aggS);
  gemm_mfma_k<64, 64, 128, true><<<(NU_N + 255) / 256, 256, 0, stream>>>(
      NU_N, aggU, xcat + 64, wz1u, b1u, tbl27, x1, ub);
  gemm_mfma_k<128, 64, 64, false><<<(NS_N + 255) / 256, 256, 0, stream>>>(
      NS_N, aggS, xs16, wz1s, b1s, nullptr, nullptr, sb);

  // ---- layer 2 ----
  gather2_k<<<(NU_N + NS_N) / 4, 256, 0, stream>>>(rpU, csrU, sb, rpS, csrS, ub,
                                                   aggU, aggS);
  gemm_mfma_k<128, 128, 128, false><<<(NU_N + 255) / 256, 256, 0, stream>>>(
      NU_N, aggU, ub, wz2u, b2u, nullptr, nullptr, ub);
  gemm_mfma_k<128, 128, 128, false><<<(NS_N + 255) / 256, 256, 0, stream>>>(
      NS_N, aggS, sb, wz2s, b2s, nullptr, nullptr, sb);

  // ---- final linear + sigmoid ----
  final_k<<<(M_N * 64 + 255) / 256, 256, 0, stream>>>(ub, sb, mu, ms, lw, lb, out);
}

// Round 9
// 687.009 us; speedup vs baseline: 5.8144x; 1.0220x over previous
//
#include <hip/hip_runtime.h>
#include <math.h>

#define NU_N 200000
#define NS_N 50000
#define E_N  1000000
#define M_N  100000
#define NBU 782   // ceil((NU+1)/256)
#define NBS 196   // ceil((NS+1)/256)
#define NSLICE 512
#define ECH 1954  // ceil(E_N / NSLICE)

typedef __attribute__((ext_vector_type(8))) short short8;
typedef __attribute__((ext_vector_type(16))) float f32x16;
typedef unsigned short ushort_t;
typedef unsigned int uint_t;

// ---- workspace layout (bytes), ~197 MB ----
static constexpr size_t OFF_AGGU  = 0;             // NU x 128 bf16
static constexpr size_t OFF_AGGS  = 51200000;      // NS x 128 bf16
static constexpr size_t OFF_U     = 64000000;      // (NU+1) x 128 bf16 (u1/u2 + zero pad row)
static constexpr size_t OFF_S     = 115200512;     // (NS+1) x 128 bf16
static constexpr size_t OFF_XCAT  = 128001024;     // (NU+1) x 128 bf16 = [age||gen||xu]
static constexpr size_t OFF_XS16  = 179201536;     // (NS+1) x 64 bf16
static constexpr size_t OFF_TBL27 = 185601792;     // 27 x 128 f32
static constexpr size_t OFF_WZ1U  = 185615616;     // K=128 swizzled bf16
static constexpr size_t OFF_WZ1S  = 185648384;     // K=192
static constexpr size_t OFF_WZ2U  = 185697536;     // K=256
static constexpr size_t OFF_WZ2S  = 185763072;     // K=256
static constexpr size_t OFF_RPU   = 185828608;     // (NU+1) int
static constexpr size_t OFF_RPS   = 186628864;     // (NS+1) int
static constexpr size_t OFF_CSRU  = 186829056;     // E int (seller srcs, dst=user)
static constexpr size_t OFF_CSRS  = 190829056;     // E int (user srcs, dst=seller)
static constexpr size_t OFF_HIST  = 194829056;     // histU|histS|curU|curS = 2,000,000 B
static constexpr size_t OFF_PART  = 196829056;     // 2 x 1024 int

__device__ inline ushort_t f2bf(float f) {
  union { float f; uint_t u; } c; c.f = f;
  uint_t r = (c.u + 0x7FFFu + ((c.u >> 16) & 1u)) >> 16;
  return (ushort_t)r;
}
__device__ inline float u2f(uint_t u) {
  union { uint_t u; float f; } c; c.u = u;
  return c.f;
}
__device__ inline float bf2f(uint_t u) { return u2f(u << 16); }

// ===================== CSR build (XCD-partitioned) =====================
// blockIdx & 7 -> XCD (round-robin dispatch heuristic). Each XCD group owns a
// 1/8 slice of destination space, streams the whole edge list (L3-backed
// re-reads), and only touches hist/cur/csr lines in its own slice -> all
// atomics and writes stay XCD-local; no cross-XCD line ping-pong.
__global__ void hist_k(const int* __restrict__ du, const int* __restrict__ ds,
                       int* __restrict__ histU, int* __restrict__ histS) {
  int xcd = blockIdx.x & 7;
  int slice = blockIdx.x >> 3;
  int uLo = xcd * (NU_N / 8), uHi = uLo + NU_N / 8;
  int sLo = xcd * (NS_N / 8), sHi = sLo + NS_N / 8;
  int e0 = slice * ECH;
  int e1 = min(E_N, e0 + ECH);
  for (int e = e0 + (int)threadIdx.x; e < e1; e += 256) {
    int u = du[e];
    if (u >= uLo && u < uHi) atomicAdd(&histU[u], 1);
    int s = ds[e];
    if (s >= sLo && s < sHi) atomicAdd(&histS[s], 1);
  }
}

// merged U+S: blocks [0,NBU) -> U, [NBU,NBU+NBS) -> S
__global__ void scan1_k(const int* __restrict__ histU, const int* __restrict__ histS,
                        int* __restrict__ rpU, int* __restrict__ rpS,
                        int* __restrict__ part) {
  __shared__ int s[256];
  int blk = blockIdx.x;
  const int* hist; int n; int* rowptr; int* pp;
  if (blk < NBU) { hist = histU; n = NU_N + 1; rowptr = rpU; pp = part; }
  else { blk -= NBU; hist = histS; n = NS_N + 1; rowptr = rpS; pp = part + 1024; }
  int t = threadIdx.x;
  int idx = blk * 256 + t;
  int v = (idx > 0 && idx < n) ? hist[idx - 1] : 0;
  s[t] = v;
  __syncthreads();
  for (int off = 1; off < 256; off <<= 1) {
    int x = (t >= off) ? s[t - off] : 0;
    __syncthreads();
    s[t] += x;
    __syncthreads();
  }
  if (idx < n) rowptr[idx] = s[t];
  if (t == 255) pp[blk] = s[255];
}

__global__ void scan2_k(int* __restrict__ part) {
  __shared__ int s[1024];
  int* pp = part + blockIdx.x * 1024;
  int nb = (blockIdx.x == 0) ? NBU : NBS;
  int t = threadIdx.x;
  int v = (t < nb) ? pp[t] : 0;
  s[t] = v;
  __syncthreads();
  for (int off = 1; off < 1024; off <<= 1) {
    int x = (t >= off) ? s[t - off] : 0;
    __syncthreads();
    s[t] += x;
    __syncthreads();
  }
  if (t < nb) pp[t] = s[t] - v;  // exclusive
}

__global__ void scan3_k(int* __restrict__ rpU, int* __restrict__ rpS,
                        const int* __restrict__ part) {
  int blk = blockIdx.x;
  int* rowptr; int n; const int* pp;
  if (blk < NBU) { rowptr = rpU; n = NU_N + 1; pp = part; }
  else { blk -= NBU; rowptr = rpS; n = NS_N + 1; pp = part + 1024; }
  int idx = blk * 256 + threadIdx.x;
  if (idx < n) rowptr[idx] += pp[blk];
}

__global__ void fill_k(const int* __restrict__ su, const int* __restrict__ ds,
                       const int* __restrict__ ss, const int* __restrict__ du,
                       const int* __restrict__ rpU, const int* __restrict__ rpS,
                       int* __restrict__ curU, int* __restrict__ curS,
                       int* __restrict__ csrU, int* __restrict__ csrS) {
  int xcd = blockIdx.x & 7;
  int slice = blockIdx.x >> 3;
  int uLo = xcd * (NU_N / 8), uHi = uLo + NU_N / 8;
  int sLo = xcd * (NS_N / 8), sHi = sLo + NS_N / 8;
  int e0 = slice * ECH;
  int e1 = min(E_N, e0 + ECH);
  for (int e = e0 + (int)threadIdx.x; e < e1; e += 256) {
    int u = du[e];
    if (u >= uLo && u < uHi) {
      int p = atomicAdd(&curU[u], 1);
      csrU[rpU[u] + p] = ss[e];
    }
    int s = ds[e];
    if (s >= sLo && s < sHi) {
      int q = atomicAdd(&curS[s], 1);
      csrS[rpS[s] + q] = su[e];
    }
  }
}

// ===================== prep: xcat/xs16 (bf16) + zero pad rows =====================
// xcat[u] = [age_emb[a] || gen_emb[g] || xu[u]] as bf16; thread = one uint2 (4 bf16)
__global__ void prep_k(const float* __restrict__ xu, const float* __restrict__ xs,
                       const int* __restrict__ x1, const float* __restrict__ age,
                       const float* __restrict__ gen,
                       ushort_t* __restrict__ xcat, ushort_t* __restrict__ xs16,
                       ushort_t* __restrict__ ub, ushort_t* __restrict__ sb) {
  int t = blockIdx.x * 256 + threadIdx.x;
  if (t < NU_N * 32) {
    int u = t >> 5, c2 = t & 31;
    float4 v;
    if (c2 < 16) {
      int2 q = ((const int2*)x1)[u];
      v = (c2 < 8) ? ((const float4*)(age + q.x * 32))[c2]
                   : ((const float4*)(gen + q.y * 32))[c2 - 8];
    } else {
      v = ((const float4*)(xu + (size_t)u * 64))[c2 - 16];
    }
    uint2 o;
    o.x = (uint_t)f2bf(v.x) | ((uint_t)f2bf(v.y) << 16);
    o.y = (uint_t)f2bf(v.z) | ((uint_t)f2bf(v.w) << 16);
    ((uint2*)xcat)[t] = o;
  } else if (t < NU_N * 32 + NS_N * 16) {
    int i = t - NU_N * 32;
    float4 v = ((const float4*)xs)[i];
    uint2 o;
    o.x = (uint_t)f2bf(v.x) | ((uint_t)f2bf(v.y) << 16);
    o.y = (uint_t)f2bf(v.z) | ((uint_t)f2bf(v.w) << 16);
    ((uint2*)xs16)[i] = o;
  } else {
    int t3 = t - NU_N * 32 - NS_N * 16;
    uint2 z; z.x = 0u; z.y = 0u;
    if (t3 < 32)       ((uint2*)xcat)[NU_N * 32 + t3] = z;
    else if (t3 < 48)  ((uint2*)xs16)[NS_N * 16 + (t3 - 32)] = z;
    else if (t3 < 80)  ((uint2*)ub)[NU_N * 32 + (t3 - 48)] = z;
    else if (t3 < 112) ((uint2*)sb)[NS_N * 32 + (t3 - 80)] = z;
  }
}

// ===================== tbl27 + merged weight swizzle =====================
__global__ void build_tbl27_k(const float* __restrict__ age, const float* __restrict__ gen,
                              const float* __restrict__ W1ur, float* __restrict__ tbl27) {
  int j = threadIdx.x;  // 0..127
  float aw[9], gw[3];
  for (int a = 0; a < 9; ++a) {
    float acc = 0.f;
    for (int k = 0; k < 32; ++k) acc += age[a * 32 + k] * W1ur[k * 128 + j];
    aw[a] = acc;
  }
  for (int g = 0; g < 3; ++g) {
    float acc = 0.f;
    for (int k = 0; k < 32; ++k) acc += gen[g * 32 + k] * W1ur[(32 + k) * 128 + j];
    gw[g] = acc;
  }
  for (int t = 0; t < 27; ++t) tbl27[t * 128 + j] = aw[t / 3] + gw[t % 3];
}

// dst[((ct*NKT+kt)*64 + lane)*8 + j] = bf16(Wcat[kt*16+(lane>>5)*8+j][ct*32+(lane&31)])
__global__ void wswz_all_k(const float* __restrict__ W1ul, const float* __restrict__ W1ur,
                           const float* __restrict__ W1sl, const float* __restrict__ W1sr,
                           const float* __restrict__ W2ul, const float* __restrict__ W2ur,
                           const float* __restrict__ W2sl, const float* __restrict__ W2sr,
                           ushort_t* __restrict__ z1u, ushort_t* __restrict__ z1s,
                           ushort_t* __restrict__ z2u, ushort_t* __restrict__ z2s) {
  int idx = blockIdx.x * 256 + threadIdx.x;
  const float *Wl, *Wr; int Km, wrOff, K, i; ushort_t* dst;
  if (idx < 16384)       { Wl = W1ul; Wr = W1ur; Km = 64;  wrOff = 64; K = 128; dst = z1u; i = idx; }
  else if (idx < 40960)  { Wl = W1sl; Wr = W1sr; Km = 128; wrOff = 0;  K = 192; dst = z1s; i = idx - 16384; }
  else if (idx < 73728)  { Wl = W2ul; Wr = W2ur; Km = 128; wrOff = 0;  K = 256; dst = z2u; i = idx - 40960; }
  else if (idx < 106496) { Wl = W2sl; Wr = W2sr; Km = 128; wrOff = 0;  K = 256; dst = z2s; i = idx - 73728; }
  else return;
  int NKT = K / 16;
  int j = i & 7, lane = (i >> 3) & 63, rest = i >> 9;
  int kt = rest % NKT, ct = rest / NKT;
  int k = kt * 16 + ((lane >> 5) << 3) + j;
  int n = ct * 32 + (lane & 31);
  float v = (k < Km) ? Wl[k * 128 + n] : Wr[(wrOff + k - Km) * 128 + n];
  dst[i] = f2bf(v);
}

// ===================== gather cores =====================
// 128-bf16 rows (256 B = 16 uint4): 4 neighbor groups x 16 lanes, dwordx4/lane,
// 8 rows in flight per wave.
__device__ inline void gmean128(int b, int e, const int* __restrict__ csr, int zrow,
                                const ushort_t* __restrict__ src,
                                ushort_t* __restrict__ dst, int lane) {
  int n = e - b;
  int g = lane >> 4, c = lane & 15;
  const uint4* s4 = (const uint4*)src;
  float acc[8];
#pragma unroll
  for (int k = 0; k < 8; ++k) acc[k] = 0.f;
  for (int base = 0; base < n; base += 8) {
    int p0 = b + base + g, p1 = p0 + 4;
    int j0 = csr[min(p0, e - 1)];
    int j1 = csr[min(p1, e - 1)];
    j0 = (p0 < e) ? j0 : zrow;
    j1 = (p1 < e) ? j1 : zrow;
    uint4 v0 = s4[j0 * 16 + c];   // row stride = 16 uint4 (256 B)
    uint4 v1 = s4[j1 * 16 + c];
    acc[0] += bf2f(v0.x); acc[1] += u2f(v0.x & 0xffff0000u);
    acc[2] += bf2f(v0.y); acc[3] += u2f(v0.y & 0xffff0000u);
    acc[4] += bf2f(v0.z); acc[5] += u2f(v0.z & 0xffff0000u);
    acc[6] += bf2f(v0.w); acc[7] += u2f(v0.w & 0xffff0000u);
    acc[0] += bf2f(v1.x); acc[1] += u2f(v1.x & 0xffff0000u);
    acc[2] += bf2f(v1.y); acc[3] += u2f(v1.y & 0xffff0000u);
    acc[4] += bf2f(v1.z); acc[5] += u2f(v1.z & 0xffff0000u);
    acc[6] += bf2f(v1.w); acc[7] += u2f(v1.w & 0xffff0000u);
  }
#pragma unroll
  for (int k = 0; k < 8; ++k) acc[k] += __shfl_down(acc[k], 32);
#pragma unroll
  for (int k = 0; k < 8; ++k) acc[k] += __shfl_down(acc[k], 16);
  if (lane < 16) {
    float inv = 1.0f / fmaxf((float)n, 1.0f);
    uint4 o;
    o.x = (uint_t)f2bf(acc[0] * inv) | ((uint_t)f2bf(acc[1] * inv) << 16);
    o.y = (uint_t)f2bf(acc[2] * inv) | ((uint_t)f2bf(acc[3] * inv) << 16);
    o.z = (uint_t)f2bf(acc[4] * inv) | ((uint_t)f2bf(acc[5] * inv) << 16);
    o.w = (uint_t)f2bf(acc[6] * inv) | ((uint_t)f2bf(acc[7] * inv) << 16);
    ((uint4*)dst)[lane] = o;
  }
}

// 64-bf16 rows (128 B = 8 uint4): 8 neighbor groups x 8 lanes, dwordx4/lane.
__device__ inline void gmean64(int b, int e, const int* __restrict__ csr, int zrow,
                               const ushort_t* __restrict__ src,
                               ushort_t* __restrict__ dst, int lane) {
  int n = e - b;
  int g = lane >> 3, c = lane & 7;
  const uint4* s4 = (const uint4*)src;
  float acc[8];
#pragma unroll
  for (int k = 0; k < 8; ++k) acc[k] = 0.f;
  for (int base = 0; base < n; base += 8) {
    int p = b + base + g;
    int j = csr[min(p, e - 1)];
    j = (p < e) ? j : zrow;
    uint4 v = s4[j * 8 + c];
    acc[0] += bf2f(v.x); acc[1] += u2f(v.x & 0xffff0000u);
    acc[2] += bf2f(v.y); acc[3] += u2f(v.y & 0xffff0000u);
    acc[4] += bf2f(v.z); acc[5] += u2f(v.z & 0xffff0000u);
    acc[6] += bf2f(v.w); acc[7] += u2f(v.w & 0xffff0000u);
  }
#pragma unroll
  for (int k = 0; k < 8; ++k) acc[k] += __shfl_down(acc[k], 32);
#pragma unroll
  for (int k = 0; k < 8; ++k) acc[k] += __shfl_down(acc[k], 16);
#pragma unroll
  for (int k = 0; k < 8; ++k) acc[k] += __shfl_down(acc[k], 8);
  if (lane < 8) {
    float inv = 1.0f / fmaxf((float)n, 1.0f);
    uint4 o;
    o.x = (uint_t)f2bf(acc[0] * inv) | ((uint_t)f2bf(acc[1] * inv) << 16);
    o.y = (uint_t)f2bf(acc[2] * inv) | ((uint_t)f2bf(acc[3] * inv) << 16);
    o.z = (uint_t)f2bf(acc[4] * inv) | ((uint_t)f2bf(acc[5] * inv) << 16);
    o.w = (uint_t)f2bf(acc[6] * inv) | ((uint_t)f2bf(acc[7] * inv) << 16);
    ((uint4*)dst)[lane] = o;
  }
}

// layer 1: users gather xs16 rows (64-d); sellers gather xcat rows (128-d)
__global__ void gather1_k(const int* __restrict__ rpU, const int* __restrict__ csrU,
                          const ushort_t* __restrict__ xs16,
                          const int* __restrict__ rpS, const int* __restrict__ csrS,
                          const ushort_t* __restrict__ xcat,
                          ushort_t* __restrict__ aggU, ushort_t* __restrict__ aggS) {
  int w = (blockIdx.x * blockDim.x + threadIdx.x) >> 6;
  int lane = threadIdx.x & 63;
  if (w < NU_N) {
    gmean64(rpU[w], rpU[w + 1], csrU, NS_N, xs16, aggU + (size_t)w * 64, lane);
  } else if (w < NU_N + NS_N) {
    int r = w - NU_N;
    gmean128(rpS[r], rpS[r + 1], csrS, NU_N, xcat, aggS + (size_t)r * 128, lane);
  }
}

// layer 2: users gather s1 rows; sellers gather u1 rows (both 128-d)
__global__ void gather2_k(const int* __restrict__ rpU, const int* __restrict__ csrU,
                          const ushort_t* __restrict__ s1,
                          const int* __restrict__ rpS, const int* __restrict__ csrS,
                          const ushort_t* __restrict__ u1,
                          ushort_t* __restrict__ aggU, ushort_t* __restrict__ aggS) {
  int w = (blockIdx.x * blockDim.x + threadIdx.x) >> 6;
  int lane = threadIdx.x & 63;
  if (w < NU_N) {
    gmean128(rpU[w], rpU[w + 1], csrU, NS_N, s1, aggU + (size_t)w * 128, lane);
  } else if (w < NU_N + NS_N) {
    int r = w - NU_N;
    gmean128(rpS[r], rpS[r + 1], csrS, NU_N, u1, aggS + (size_t)r * 128, lane);
  }
}

// ===================== MFMA row-GEMM (bf16 in, bf16 out) =====================
// out[nrows x 128] = relu([mean | self] @ Wswz + bias (+ tbl27))
// self stride = SSTR (xcat-strided for layer-1 user). In-place safe for layer 2.
template <int KM, int KS, int SSTR, bool TBL>
__global__ __launch_bounds__(256, 2) void gemm_mfma_k(
    int nrows, const ushort_t* __restrict__ agg, const ushort_t* self,
    const ushort_t* __restrict__ wswz, const float* __restrict__ bias,
    const float* __restrict__ tbl27, const int* __restrict__ x1, ushort_t* out) {
  constexpr int K = KM + KS;
  constexpr int NKT = K / 16;
  __shared__ short sW[K * 128];

  {
    const uint4* g4 = (const uint4*)wswz;
    uint4* s4 = (uint4*)sW;
    for (int i = threadIdx.x; i < K * 16; i += 256) s4[i] = g4[i];
  }
  __syncthreads();

  int wave = threadIdx.x >> 6, lane = threadIdx.x & 63;
  int r0 = blockIdx.x * 256 + wave * 64;
  int qk = (lane >> 5) << 3;  // k sub-offset (0 or 8)

  int ra = r0 + (lane & 31), rb = ra + 32;
  int rac = (ra < nrows) ? ra : 0, rbc = (rb < nrows) ? rb : 0;

  f32x16 acc[2][4];
#pragma unroll
  for (int rt = 0; rt < 2; ++rt)
#pragma unroll
    for (int ct = 0; ct < 4; ++ct) acc[rt][ct] = (f32x16)0.0f;

  const short8* sWv = (const short8*)sW;

#pragma unroll
  for (int kt = 0; kt < NKT; ++kt) {
    int k0 = kt * 16 + qk;
    short8 af, bf;
    if (kt * 16 < KM) {  // compile-time: mean part (KM % 16 == 0)
      af = *((const short8*)(agg + (size_t)rac * KM + k0));
      bf = *((const short8*)(agg + (size_t)rbc * KM + k0));
    } else {
      af = *((const short8*)(self + (size_t)rac * SSTR + (k0 - KM)));
      bf = *((const short8*)(self + (size_t)rbc * SSTR + (k0 - KM)));
    }
#pragma unroll
    for (int ct = 0; ct < 4; ++ct) {
      short8 wf = sWv[(ct * NKT + kt) * 64 + lane];
      acc[0][ct] = __builtin_amdgcn_mfma_f32_32x32x16_bf16(af, wf, acc[0][ct], 0, 0, 0);
      acc[1][ct] = __builtin_amdgcn_mfma_f32_32x32x16_bf16(bf, wf, acc[1][ct], 0, 0, 0);
    }
  }

  // epilogue: C layout col=lane&31, row=(reg&3)+8*(reg>>2)+4*(lane>>5)
  int nloc = lane & 31;
  float bn[4];
#pragma unroll
  for (int ct = 0; ct < 4; ++ct) bn[ct] = bias[ct * 32 + nloc];
  int rowq = 4 * (lane >> 5);
#pragma unroll
  for (int rt = 0; rt < 2; ++rt) {
#pragma unroll
    for (int reg = 0; reg < 16; ++reg) {
      int row = r0 + rt * 32 + (reg & 3) + 8 * (reg >> 2) + rowq;
      if (row < nrows) {
        const float* tp = nullptr;
        if (TBL) {
          int a = x1[2 * row], g = x1[2 * row + 1];
          tp = tbl27 + (a * 3 + g) * 128 + nloc;
        }
#pragma unroll
        for (int ct = 0; ct < 4; ++ct) {
          float v = acc[rt][ct][reg] + bn[ct];
          if (TBL) v += tp[ct * 32];
          out[(size_t)row * 128 + ct * 32 + nloc] = f2bf(fmaxf(v, 0.0f));
        }
      }
    }
  }
}

// ===================== final =====================
__global__ void final_k(const ushort_t* __restrict__ u2, const ushort_t* __restrict__ s2,
                        const int* __restrict__ mu, const int* __restrict__ ms,
                        const float* __restrict__ lw, const float* __restrict__ lb,
                        float* __restrict__ out) {
  int w = (blockIdx.x * blockDim.x + threadIdx.x) >> 6;
  int lane = threadIdx.x & 63;
  if (w >= M_N) return;
  int iu = mu[w], is = ms[w];
  uint_t a = ((const uint_t*)(u2 + (size_t)iu * 128))[lane];
  uint_t b = ((const uint_t*)(s2 + (size_t)is * 128))[lane];
  float p = bf2f(a & 0xffffu) * lw[2 * lane] + bf2f(a >> 16) * lw[2 * lane + 1]
          + bf2f(b & 0xffffu) * lw[128 + 2 * lane] + bf2f(b >> 16) * lw[129 + 2 * lane];
#pragma unroll
  for (int off = 32; off > 0; off >>= 1) p += __shfl_down(p, off, 64);
  if (lane == 0) out[w] = 1.0f / (1.0f + expf(-(p + lb[0])));
}

extern "C" void kernel_launch(void* const* d_in, const int* in_sizes, int n_in,
                              void* d_out, int out_size, void* d_ws, size_t ws_size,
                              hipStream_t stream) {
  const float* xu   = (const float*)d_in[0];
  const float* xs   = (const float*)d_in[1];
  const int*   x1   = (const int*)d_in[2];
  const int*   su   = (const int*)d_in[3];
  const int*   ds   = (const int*)d_in[4];
  const int*   ss   = (const int*)d_in[5];
  const int*   du   = (const int*)d_in[6];
  const int*   mu   = (const int*)d_in[7];
  const int*   ms   = (const int*)d_in[8];
  const float* age  = (const float*)d_in[9];
  const float* gen  = (const float*)d_in[10];
  const float* W1ul = (const float*)d_in[11];
  const float* W1ur = (const float*)d_in[12];
  const float* b1u  = (const float*)d_in[13];
  const float* W1sl = (const float*)d_in[14];
  const float* W1sr = (const float*)d_in[15];
  const float* b1s  = (const float*)d_in[16];
  const float* W2ul = (const float*)d_in[17];
  const float* W2ur = (const float*)d_in[18];
  const float* b2u  = (const float*)d_in[19];
  const float* W2sl = (const float*)d_in[20];
  const float* W2sr = (const float*)d_in[21];
  const float* b2s  = (const float*)d_in[22];
  const float* lw   = (const float*)d_in[23];
  const float* lb   = (const float*)d_in[24];

  char* w = (char*)d_ws;
  ushort_t* aggU = (ushort_t*)(w + OFF_AGGU);
  ushort_t* aggS = (ushort_t*)(w + OFF_AGGS);
  ushort_t* ub   = (ushort_t*)(w + OFF_U);
  ushort_t* sb   = (ushort_t*)(w + OFF_S);
  ushort_t* xcat = (ushort_t*)(w + OFF_XCAT);
  ushort_t* xs16 = (ushort_t*)(w + OFF_XS16);
  float* tbl27   = (float*)(w + OFF_TBL27);
  ushort_t* wz1u = (ushort_t*)(w + OFF_WZ1U);
  ushort_t* wz1s = (ushort_t*)(w + OFF_WZ1S);
  ushort_t* wz2u = (ushort_t*)(w + OFF_WZ2U);
  ushort_t* wz2s = (ushort_t*)(w + OFF_WZ2S);
  int* rpU   = (int*)(w + OFF_RPU);
  int* rpS   = (int*)(w + OFF_RPS);
  int* csrU  = (int*)(w + OFF_CSRU);
  int* csrS  = (int*)(w + OFF_CSRS);
  int* histU = (int*)(w + OFF_HIST);
  int* histS = (int*)(w + OFF_HIST + 800000);
  int* curU  = (int*)(w + OFF_HIST + 1000000);
  int* curS  = (int*)(w + OFF_HIST + 1800000);
  int* part  = (int*)(w + OFF_PART);
  float* out = (float*)d_out;

  // ---- CSR build (once; shared by both layers; XCD-partitioned) ----
  hipMemsetAsync(w + OFF_HIST, 0, 2000000, stream);  // histU|histS|curU|curS
  hist_k<<<8 * NSLICE, 256, 0, stream>>>(du, ds, histU, histS);
  scan1_k<<<NBU + NBS, 256, 0, stream>>>(histU, histS, rpU, rpS, part);
  scan2_k<<<2, 1024, 0, stream>>>(part);
  scan3_k<<<NBU + NBS, 256, 0, stream>>>(rpU, rpS, part);
  fill_k<<<8 * NSLICE, 256, 0, stream>>>(su, ds, ss, du, rpU, rpS, curU, curS, csrU, csrS);

  // ---- prep: bf16 features (+pads) + tables + swizzled weights ----
  prep_k<<<(NU_N * 32 + NS_N * 16 + 112 + 255) / 256, 256, 0, stream>>>(
      xu, xs, x1, age, gen, xcat, xs16, ub, sb);
  build_tbl27_k<<<1, 128, 0, stream>>>(age, gen, W1ur, tbl27);
  wswz_all_k<<<416, 256, 0, stream>>>(W1ul, W1ur, W1sl, W1sr, W2ul, W2ur, W2sl, W2sr,
                                      wz1u, wz1s, wz2u, wz2s);

  // ---- layer 1 ----
  gather1_k<<<(NU_N + NS_N) / 4, 256, 0, stream>>>(rpU, csrU, xs16, rpS, csrS, xcat,
                                                   aggU, aggS);
  gemm_mfma_k<64, 64, 128, true><<<(NU_N + 255) / 256, 256, 0, stream>>>(
      NU_N, aggU, xcat + 64, wz1u, b1u, tbl27, x1, ub);
  gemm_mfma_k<128, 64, 64, false><<<(NS_N + 255) / 256, 256, 0, stream>>>(
      NS_N, aggS, xs16, wz1s, b1s, nullptr, nullptr, sb);

  // ---- layer 2 ----
  gather2_k<<<(NU_N + NS_N) / 4, 256, 0, stream>>>(rpU, csrU, sb, rpS, csrS, ub,
                                                   aggU, aggS);
  gemm_mfma_k<128, 128, 128, false><<<(NU_N + 255) / 256, 256, 0, stream>>>(
      NU_N, aggU, ub, wz2u, b2u, nullptr, nullptr, ub);
  gemm_mfma_k<128, 128, 128, false><<<(NS_N + 255) / 256, 256, 0, stream>>>(
      NS_N, aggS, sb, wz2s, b2s, nullptr, nullptr, sb);

  // ---- final linear + sigmoid ----
  final_k<<<(M_N * 64 + 255) / 256, 256, 0, stream>>>(ub, sb, mu, ms, lw, lb, out);
}

// Round 10
// 673.391 us; speedup vs baseline: 5.9320x; 1.0202x over previous
//
#include <hip/hip_runtime.h>
#include <math.h>

#define NU_N 200000
#define NS_N 50000
#define E_N  1000000
#define M_N  100000
#define NBU 782    // ceil((NU+1)/256) scan blocks
#define NBS 196    // ceil((NS+1)/256)
#define NUBG 782   // ceil(NU/256) gemm blocks
#define NSBG 196   // ceil(NS/256)
#define NSLICE 512
#define ECH 1954   // ceil(E_N / NSLICE)

typedef __attribute__((ext_vector_type(8))) short short8;
typedef __attribute__((ext_vector_type(16))) float f32x16;
typedef unsigned short ushort_t;
typedef unsigned int uint_t;

// ---- workspace layout (bytes), ~174 MB ----
static constexpr size_t OFF_AGGU  = 0;             // NU x 128 bf16 (L1: stride 64, L2: 128)
static constexpr size_t OFF_AGGS  = 51200000;      // NS x 128 bf16 (L1: stride 80, L2: 128)
static constexpr size_t OFF_U     = 64000000;      // (NU+1) x 128 bf16 (+zero pad row)
static constexpr size_t OFF_S     = 115200256;     // (NS+1) x 128 bf16
static constexpr size_t OFF_XU16  = 128000512;     // (NU+1) x 64 bf16
static constexpr size_t OFF_XS16  = 153600640;     // (NS+1) x 64 bf16
static constexpr size_t OFF_TBL27 = 160000768;     // 27 x 128 f32
static constexpr size_t OFF_Z1U   = 160014592;     // K=128 swizzled bf16
static constexpr size_t OFF_Z1S   = 160047360;     // K=144 (64 xu | 9 age | 3 gen | 4 pad | 64 self)
static constexpr size_t OFF_Z2U   = 160084224;     // K=256
static constexpr size_t OFF_Z2S   = 160149760;     // K=256
static constexpr size_t OFF_RPU   = 160215296;     // (NU+1) int
static constexpr size_t OFF_RPS   = 161015312;     // (NS+1) int
static constexpr size_t OFF_CSRU  = 161215328;     // (E+8) int
static constexpr size_t OFF_CSRS  = 165215360;     // (E+8) int
static constexpr size_t OFF_HIST  = 169215392;     // histU|histS|curU|curS|hist12 = 4,400,000
static constexpr size_t OFF_PART  = 173615392;     // 2 x 1024 int

__device__ inline ushort_t f2bf(float f) {
  union { float f; uint_t u; } c; c.f = f;
  uint_t r = (c.u + 0x7FFFu + ((c.u >> 16) & 1u)) >> 16;
  return (ushort_t)r;
}
__device__ inline float u2f(uint_t u) {
  union { uint_t u; float f; } c; c.u = u;
  return c.f;
}
__device__ inline float bf2f(uint_t u) { return u2f(u << 16); }

// ===================== CSR build (XCD-partitioned) =====================
__global__ void hist_k(const int* __restrict__ du, const int* __restrict__ ds,
                       int* __restrict__ histU, int* __restrict__ histS) {
  int xcd = blockIdx.x & 7;
  int slice = blockIdx.x >> 3;
  int uLo = xcd * (NU_N / 8), uHi = uLo + NU_N / 8;
  int sLo = xcd * (NS_N / 8), sHi = sLo + NS_N / 8;
  int e0 = slice * ECH;
  int e1 = min(E_N, e0 + ECH);
  for (int e = e0 + (int)threadIdx.x; e < e1; e += 256) {
    int u = du[e];
    if (u >= uLo && u < uHi) atomicAdd(&histU[u], 1);
    int s = ds[e];
    if (s >= sLo && s < sHi) atomicAdd(&histS[s], 1);
  }
}

__global__ void scan1_k(const int* __restrict__ histU, const int* __restrict__ histS,
                        int* __restrict__ rpU, int* __restrict__ rpS,
                        int* __restrict__ part) {
  __shared__ int s[256];
  int blk = blockIdx.x;
  const int* hist; int n; int* rowptr; int* pp;
  if (blk < NBU) { hist = histU; n = NU_N + 1; rowptr = rpU; pp = part; }
  else { blk -= NBU; hist = histS; n = NS_N + 1; rowptr = rpS; pp = part + 1024; }
  int t = threadIdx.x;
  int idx = blk * 256 + t;
  int v = (idx > 0 && idx < n) ? hist[idx - 1] : 0;
  s[t] = v;
  __syncthreads();
  for (int off = 1; off < 256; off <<= 1) {
    int x = (t >= off) ? s[t - off] : 0;
    __syncthreads();
    s[t] += x;
    __syncthreads();
  }
  if (idx < n) rowptr[idx] = s[t];
  if (t == 255) pp[blk] = s[255];
}

__global__ void scan2_k(int* __restrict__ part) {
  __shared__ int s[1024];
  int* pp = part + blockIdx.x * 1024;
  int nb = (blockIdx.x == 0) ? NBU : NBS;
  int t = threadIdx.x;
  int v = (t < nb) ? pp[t] : 0;
  s[t] = v;
  __syncthreads();
  for (int off = 1; off < 1024; off <<= 1) {
    int x = (t >= off) ? s[t - off] : 0;
    __syncthreads();
    s[t] += x;
    __syncthreads();
  }
  if (t < nb) pp[t] = s[t] - v;  // exclusive
}

__global__ void scan3_k(int* __restrict__ rpU, int* __restrict__ rpS,
                        const int* __restrict__ part) {
  int blk = blockIdx.x;
  int* rowptr; int n; const int* pp;
  if (blk < NBU) { rowptr = rpU; n = NU_N + 1; pp = part; }
  else { blk -= NBU; rowptr = rpS; n = NS_N + 1; pp = part + 1024; }
  int idx = blk * 256 + threadIdx.x;
  if (idx < n) rowptr[idx] += pp[blk];
}

// fill + per-seller 12-bin age/gen histogram (XCD-local atomics)
__global__ void fill_k(const int* __restrict__ su, const int* __restrict__ ds,
                       const int* __restrict__ ss, const int* __restrict__ du,
                       const int* __restrict__ rpU, const int* __restrict__ rpS,
                       const int* __restrict__ x1,
                       int* __restrict__ curU, int* __restrict__ curS,
                       int* __restrict__ csrU, int* __restrict__ csrS,
                       int* __restrict__ hist12) {
  int xcd = blockIdx.x & 7;
  int slice = blockIdx.x >> 3;
  int uLo = xcd * (NU_N / 8), uHi = uLo + NU_N / 8;
  int sLo = xcd * (NS_N / 8), sHi = sLo + NS_N / 8;
  int e0 = slice * ECH;
  int e1 = min(E_N, e0 + ECH);
  const int2* x1p = (const int2*)x1;
  for (int e = e0 + (int)threadIdx.x; e < e1; e += 256) {
    int u = du[e];
    if (u >= uLo && u < uHi) {
      int p = atomicAdd(&curU[u], 1);
      csrU[rpU[u] + p] = ss[e];
    }
    int s = ds[e];
    if (s >= sLo && s < sHi) {
      int q = atomicAdd(&curS[s], 1);
      int usrc = su[e];
      csrS[rpS[s] + q] = usrc;
      int2 ag = x1p[usrc];
      atomicAdd(&hist12[s * 12 + ag.x], 1);
      atomicAdd(&hist12[s * 12 + 9 + ag.y], 1);
    }
  }
}

// ===================== merged prep: bf16 feats + pads + tbl27 + weight swizzles ====
// thread ranges: [0,3.2M) xu16 | xs16 | pads | tbl27 | z1u | z1s | z2u | z2s
__global__ void prep_all_k(const float* __restrict__ xu, const float* __restrict__ xs,
                           const int* __restrict__ x1, const float* __restrict__ age,
                           const float* __restrict__ gen,
                           const float* __restrict__ W1ul, const float* __restrict__ W1ur,
                           const float* __restrict__ W1sl, const float* __restrict__ W1sr,
                           const float* __restrict__ W2ul, const float* __restrict__ W2ur,
                           const float* __restrict__ W2sl, const float* __restrict__ W2sr,
                           ushort_t* __restrict__ xu16, ushort_t* __restrict__ xs16,
                           ushort_t* __restrict__ ub, ushort_t* __restrict__ sb,
                           float* __restrict__ tbl27,
                           ushort_t* __restrict__ z1u, ushort_t* __restrict__ z1s,
                           ushort_t* __restrict__ z2u, ushort_t* __restrict__ z2s) {
  int t = blockIdx.x * 256 + threadIdx.x;
  if (t < 4000000) {  // xu16 (3.2M float4s) then xs16 (800k)
    const float* src = (t < 3200000) ? xu : xs;
    ushort_t* dst = (t < 3200000) ? xu16 : xs16;
    int i = (t < 3200000) ? t : t - 3200000;
    float4 v = ((const float4*)src)[i];
    uint2 o;
    o.x = (uint_t)f2bf(v.x) | ((uint_t)f2bf(v.y) << 16);
    o.y = (uint_t)f2bf(v.z) | ((uint_t)f2bf(v.w) << 16);
    ((uint2*)dst)[i] = o;
  } else if (t < 4000096) {  // zero pad rows
    int t3 = t - 4000000;
    uint2 z; z.x = 0u; z.y = 0u;
    if (t3 < 16)       ((uint2*)xu16)[NU_N * 16 + t3] = z;
    else if (t3 < 32)  ((uint2*)xs16)[NS_N * 16 + (t3 - 16)] = z;
    else if (t3 < 64)  ((uint2*)ub)[NU_N * 32 + (t3 - 32)] = z;
    else               ((uint2*)sb)[NS_N * 32 + (t3 - 64)] = z;
  } else if (t < 4003552) {  // tbl27: 27 x 128
    int i = t - 4000096;
    int tt = i >> 7, j = i & 127;
    int a = tt / 3, g = tt % 3;
    float acc = 0.f;
    for (int k = 0; k < 32; ++k) acc += age[a * 32 + k] * W1ur[k * 128 + j];
    for (int k = 0; k < 32; ++k) acc += gen[g * 32 + k] * W1ur[(32 + k) * 128 + j];
    tbl27[i] = acc;
  } else if (t < 4019936) {  // z1u: K=128 (W1ul 64 | W1ur[64:128])
    int i = t - 4003552;
    int j = i & 7, lane = (i >> 3) & 63, rest = i >> 9;
    int kt = rest % 8, ct = rest / 8;
    int k = kt * 16 + ((lane >> 5) << 3) + j;
    int n = ct * 32 + (lane & 31);
    float v = (k < 64) ? W1ul[k * 128 + n] : W1ur[k * 128 + n];
    z1u[i] = f2bf(v);
  } else if (t < 4038368) {  // z1s: K=144 (W1sl[64:128] | ageW 9 | genW 3 | 0 x4 | W1sr 64)
    int i = t - 4019936;
    int j = i & 7, lane = (i >> 3) & 63, rest = i >> 9;
    int kt = rest % 9, ct = rest / 9;
    int k = kt * 16 + ((lane >> 5) << 3) + j;
    int n = ct * 32 + (lane & 31);
    float v;
    if (k < 64) v = W1sl[(64 + k) * 128 + n];
    else if (k < 73) {
      int a = k - 64; v = 0.f;
      for (int kk = 0; kk < 32; ++kk) v += age[a * 32 + kk] * W1sl[kk * 128 + n];
    } else if (k < 76) {
      int g = k - 73; v = 0.f;
      for (int kk = 0; kk < 32; ++kk) v += gen[g * 32 + kk] * W1sl[(32 + kk) * 128 + n];
    } else if (k < 80) v = 0.f;
    else v = W1sr[(k - 80) * 128 + n];
    z1s[i] = f2bf(v);
  } else if (t < 4103904) {  // z2u then z2s: K=256
    int i = t - 4038368;
    const float *Wl, *Wr; ushort_t* dst;
    if (i < 32768) { Wl = W2ul; Wr = W2ur; dst = z2u; }
    else { Wl = W2sl; Wr = W2sr; dst = z2s; i -= 32768; }
    int j = i & 7, lane = (i >> 3) & 63, rest = i >> 9;
    int kt = rest % 16, ct = rest / 16;
    int k = kt * 16 + ((lane >> 5) << 3) + j;
    int n = ct * 32 + (lane & 31);
    float v = (k < 128) ? Wl[k * 128 + n] : Wr[(k - 128) * 128 + n];
    dst[i] = f2bf(v);
  }
}

// ===================== gather cores (body/tail + csr prefetch) =====================
#define ACC8(V)                                              \
  acc[0] += bf2f(V.x); acc[1] += u2f(V.x & 0xffff0000u);     \
  acc[2] += bf2f(V.y); acc[3] += u2f(V.y & 0xffff0000u);     \
  acc[4] += bf2f(V.z); acc[5] += u2f(V.z & 0xffff0000u);     \
  acc[6] += bf2f(V.w); acc[7] += u2f(V.w & 0xffff0000u);

// 128-bf16 rows (256 B): 4 neighbor groups x 16 lanes, 8 rows/iter in flight.
__device__ inline void gmean128(int b, int e, const int* __restrict__ csr, int zrow,
                                const ushort_t* __restrict__ src,
                                ushort_t* __restrict__ dst, int lane) {
  int n = e - b;
  int g = lane >> 4, c = lane & 15;
  const uint4* s4 = (const uint4*)src;
  float acc[8];
#pragma unroll
  for (int k = 0; k < 8; ++k) acc[k] = 0.f;
  int nb = n & ~7;
  if (nb) {
    int p0 = b + g, p1 = p0 + 4;
    int j0 = csr[p0], j1 = csr[p1];
    for (int base = 8;; base += 8) {
      uint4 v0 = s4[(size_t)j0 * 16 + c];
      uint4 v1 = s4[(size_t)j1 * 16 + c];
      bool more = base < nb;
      if (more) { j0 = csr[p0 + base]; j1 = csr[p1 + base]; }
      ACC8(v0); ACC8(v1);
      if (!more) break;
    }
  }
  if (nb < n) {  // masked tail (csr padded +8 -> reads safe; index redirected to zero row)
    int p0 = b + nb + g, p1 = p0 + 4;
    int j0 = csr[p0]; j0 = (p0 < e) ? j0 : zrow;
    int j1 = csr[p1]; j1 = (p1 < e) ? j1 : zrow;
    uint4 v0 = s4[(size_t)j0 * 16 + c];
    uint4 v1 = s4[(size_t)j1 * 16 + c];
    ACC8(v0); ACC8(v1);
  }
#pragma unroll
  for (int k = 0; k < 8; ++k) acc[k] += __shfl_down(acc[k], 32);
#pragma unroll
  for (int k = 0; k < 8; ++k) acc[k] += __shfl_down(acc[k], 16);
  if (lane < 16) {
    float inv = 1.0f / fmaxf((float)n, 1.0f);
    uint4 o;
    o.x = (uint_t)f2bf(acc[0] * inv) | ((uint_t)f2bf(acc[1] * inv) << 16);
    o.y = (uint_t)f2bf(acc[2] * inv) | ((uint_t)f2bf(acc[3] * inv) << 16);
    o.z = (uint_t)f2bf(acc[4] * inv) | ((uint_t)f2bf(acc[5] * inv) << 16);
    o.w = (uint_t)f2bf(acc[6] * inv) | ((uint_t)f2bf(acc[7] * inv) << 16);
    ((uint4*)dst)[lane] = o;
  }
}

// 64-bf16 rows (128 B): 8 neighbor groups x 8 lanes, 8 rows/iter.
// If h12 != nullptr: dst row is 80-d — append 12 count features (c/n) + 4 zeros.
__device__ inline void gmean64(int b, int e, const int* __restrict__ csr, int zrow,
                               const ushort_t* __restrict__ src,
                               const int* __restrict__ h12,
                               ushort_t* __restrict__ dst, int lane) {
  int n = e - b;
  int g = lane >> 3, c = lane & 7;
  const uint4* s4 = (const uint4*)src;
  float acc[8];
#pragma unroll
  for (int k = 0; k < 8; ++k) acc[k] = 0.f;
  int nb = n & ~7;
  if (nb) {
    int p = b + g;
    int j = csr[p];
    for (int base = 8;; base += 8) {
      uint4 v = s4[(size_t)j * 8 + c];
      bool more = base < nb;
      if (more) j = csr[p + base];
      ACC8(v);
      if (!more) break;
    }
  }
  if (nb < n) {
    int p = b + nb + g;
    int j = csr[p]; j = (p < e) ? j : zrow;
    uint4 v = s4[(size_t)j * 8 + c];
    ACC8(v);
  }
#pragma unroll
  for (int k = 0; k < 8; ++k) acc[k] += __shfl_down(acc[k], 32);
#pragma unroll
  for (int k = 0; k < 8; ++k) acc[k] += __shfl_down(acc[k], 16);
#pragma unroll
  for (int k = 0; k < 8; ++k) acc[k] += __shfl_down(acc[k], 8);
  float inv = 1.0f / fmaxf((float)n, 1.0f);
  if (lane < 8) {
    uint4 o;
    o.x = (uint_t)f2bf(acc[0] * inv) | ((uint_t)f2bf(acc[1] * inv) << 16);
    o.y = (uint_t)f2bf(acc[2] * inv) | ((uint_t)f2bf(acc[3] * inv) << 16);
    o.z = (uint_t)f2bf(acc[4] * inv) | ((uint_t)f2bf(acc[5] * inv) << 16);
    o.w = (uint_t)f2bf(acc[6] * inv) | ((uint_t)f2bf(acc[7] * inv) << 16);
    ((uint4*)dst)[lane] = o;
  } else if (h12 && lane < 16) {
    int ci = 2 * (lane - 8);
    float c0 = (ci < 12) ? (float)h12[ci] : 0.f;
    float c1 = (ci + 1 < 12) ? (float)h12[ci + 1] : 0.f;
    ((uint_t*)dst)[32 + (lane - 8)] =
        (uint_t)f2bf(c0 * inv) | ((uint_t)f2bf(c1 * inv) << 16);
  }
}

// layer 1: users mean xs16 (64-d); sellers mean xu16 (64-d) + 12 count feats -> 80-d
__global__ void gather1_k(const int* __restrict__ rpU, const int* __restrict__ csrU,
                          const ushort_t* __restrict__ xs16,
                          const int* __restrict__ rpS, const int* __restrict__ csrS,
                          const ushort_t* __restrict__ xu16,
                          const int* __restrict__ hist12,
                          ushort_t* __restrict__ aggU, ushort_t* __restrict__ aggS) {
  int w = (blockIdx.x * blockDim.x + threadIdx.x) >> 6;
  int lane = threadIdx.x & 63;
  if (w < NU_N) {
    gmean64(rpU[w], rpU[w + 1], csrU, NS_N, xs16, nullptr, aggU + (size_t)w * 64, lane);
  } else if (w < NU_N + NS_N) {
    int r = w - NU_N;
    gmean64(rpS[r], rpS[r + 1], csrS, NU_N, xu16, hist12 + (size_t)r * 12,
            aggS + (size_t)r * 80, lane);
  }
}

// layer 2: users mean s1 rows; sellers mean u1 rows (both 128-d)
__global__ void gather2_k(const int* __restrict__ rpU, const int* __restrict__ csrU,
                          const ushort_t* __restrict__ s1,
                          const int* __restrict__ rpS, const int* __restrict__ csrS,
                          const ushort_t* __restrict__ u1,
                          ushort_t* __restrict__ aggU, ushort_t* __restrict__ aggS) {
  int w = (blockIdx.x * blockDim.x + threadIdx.x) >> 6;
  int lane = threadIdx.x & 63;
  if (w < NU_N) {
    gmean128(rpU[w], rpU[w + 1], csrU, NS_N, s1, aggU + (size_t)w * 128, lane);
  } else if (w < NU_N + NS_N) {
    int r = w - NU_N;
    gmean128(rpS[r], rpS[r + 1], csrS, NU_N, u1, aggS + (size_t)r * 128, lane);
  }
}

// ===================== MFMA row-GEMM core (bf16 in, bf16 out) =====================
template <int KM, int KS, int SSTR, bool TBL>
__device__ __forceinline__ void gemm_core(
    short* sW, int bid, int nrows, const ushort_t* __restrict__ agg,
    const ushort_t* self, const ushort_t* __restrict__ wswz,
    const float* __restrict__ bias, const float* __restrict__ tbl27,
    const int* __restrict__ x1, ushort_t* out) {
  constexpr int K = KM + KS;
  constexpr int NKT = K / 16;
  {
    const uint4* g4 = (const uint4*)wswz;
    uint4* s4 = (uint4*)sW;
    for (int i = threadIdx.x; i < K * 16; i += 256) s4[i] = g4[i];
  }
  __syncthreads();

  int wave = threadIdx.x >> 6, lane = threadIdx.x & 63;
  int r0 = bid * 256 + wave * 64;
  int qk = (lane >> 5) << 3;

  int ra = r0 + (lane & 31), rb = ra + 32;
  int rac = (ra < nrows) ? ra : 0, rbc = (rb < nrows) ? rb : 0;

  f32x16 acc[2][4];
#pragma unroll
  for (int rt = 0; rt < 2; ++rt)
#pragma unroll
    for (int ct = 0; ct < 4; ++ct) acc[rt][ct] = (f32x16)0.0f;

  const short8* sWv = (const short8*)sW;

#pragma unroll
  for (int kt = 0; kt < NKT; ++kt) {
    int k0 = kt * 16 + qk;
    short8 af, bf;
    if (kt * 16 < KM) {
      af = *((const short8*)(agg + (size_t)rac * KM + k0));
      bf = *((const short8*)(agg + (size_t)rbc * KM + k0));
    } else {
      af = *((const short8*)(self + (size_t)rac * SSTR + (k0 - KM)));
      bf = *((const short8*)(self + (size_t)rbc * SSTR + (k0 - KM)));
    }
#pragma unroll
    for (int ct = 0; ct < 4; ++ct) {
      short8 wf = sWv[(ct * NKT + kt) * 64 + lane];
      acc[0][ct] = __builtin_amdgcn_mfma_f32_32x32x16_bf16(af, wf, acc[0][ct], 0, 0, 0);
      acc[1][ct] = __builtin_amdgcn_mfma_f32_32x32x16_bf16(bf, wf, acc[1][ct], 0, 0, 0);
    }
  }

  int nloc = lane & 31;
  float bn[4];
#pragma unroll
  for (int ct = 0; ct < 4; ++ct) bn[ct] = bias[ct * 32 + nloc];
  int rowq = 4 * (lane >> 5);
#pragma unroll
  for (int rt = 0; rt < 2; ++rt) {
#pragma unroll
    for (int reg = 0; reg < 16; ++reg) {
      int row = r0 + rt * 32 + (reg & 3) + 8 * (reg >> 2) + rowq;
      if (row < nrows) {
        const float* tp = nullptr;
        if (TBL) {
          int a = x1[2 * row], g = x1[2 * row + 1];
          tp = tbl27 + (a * 3 + g) * 128 + nloc;
        }
#pragma unroll
        for (int ct = 0; ct < 4; ++ct) {
          float v = acc[rt][ct][reg] + bn[ct];
          if (TBL) v += tp[ct * 32];
          out[(size_t)row * 128 + ct * 32 + nloc] = f2bf(fmaxf(v, 0.0f));
        }
      }
    }
  }
}

// merged layer-1 GEMM: blocks [0,NUBG) user (K=128), [NUBG,+NSBG) seller (K=144)
__global__ __launch_bounds__(256, 2) void gemm1_k(
    const ushort_t* __restrict__ aggU, const ushort_t* __restrict__ aggS,
    const ushort_t* __restrict__ xu16, const ushort_t* __restrict__ xs16,
    const ushort_t* __restrict__ z1u, const ushort_t* __restrict__ z1s,
    const float* __restrict__ b1u, const float* __restrict__ b1s,
    const float* __restrict__ tbl27, const int* __restrict__ x1,
    ushort_t* __restrict__ ub, ushort_t* __restrict__ sb) {
  extern __shared__ short smem[];
  if (blockIdx.x < NUBG)
    gemm_core<64, 64, 64, true>(smem, blockIdx.x, NU_N, aggU, xu16, z1u, b1u, tbl27, x1, ub);
  else
    gemm_core<80, 64, 64, false>(smem, blockIdx.x - NUBG, NS_N, aggS, xs16, z1s, b1s,
                                 nullptr, nullptr, sb);
}

// merged layer-2 GEMM (both K=256, in-place)
__global__ __launch_bounds__(256, 2) void gemm2_k(
    const ushort_t* __restrict__ aggU, const ushort_t* __restrict__ aggS,
    const ushort_t* __restrict__ z2u, const ushort_t* __restrict__ z2s,
    const float* __restrict__ b2u, const float* __restrict__ b2s,
    ushort_t* ub, ushort_t* sb) {
  extern __shared__ short smem[];
  if (blockIdx.x < NUBG)
    gemm_core<128, 128, 128, false>(smem, blockIdx.x, NU_N, aggU, ub, z2u, b2u,
                                    nullptr, nullptr, ub);
  else
    gemm_core<128, 128, 128, false>(smem, blockIdx.x - NUBG, NS_N, aggS, sb, z2s, b2s,
                                    nullptr, nullptr, sb);
}

// ===================== final =====================
__global__ void final_k(const ushort_t* __restrict__ u2, const ushort_t* __restrict__ s2,
                        const int* __restrict__ mu, const int* __restrict__ ms,
                        const float* __restrict__ lw, const float* __restrict__ lb,
                        float* __restrict__ out) {
  int w = (blockIdx.x * blockDim.x + threadIdx.x) >> 6;
  int lane = threadIdx.x & 63;
  if (w >= M_N) return;
  int iu = mu[w], is = ms[w];
  uint_t a = ((const uint_t*)(u2 + (size_t)iu * 128))[lane];
  uint_t b = ((const uint_t*)(s2 + (size_t)is * 128))[lane];
  float p = bf2f(a & 0xffffu) * lw[2 * lane] + bf2f(a >> 16) * lw[2 * lane + 1]
          + bf2f(b & 0xffffu) * lw[128 + 2 * lane] + bf2f(b >> 16) * lw[129 + 2 * lane];
#pragma unroll
  for (int off = 32; off > 0; off >>= 1) p += __shfl_down(p, off, 64);
  if (lane == 0) out[w] = 1.0f / (1.0f + expf(-(p + lb[0])));
}

extern "C" void kernel_launch(void* const* d_in, const int* in_sizes, int n_in,
                              void* d_out, int out_size, void* d_ws, size_t ws_size,
                              hipStream_t stream) {
  const float* xu   = (const float*)d_in[0];
  const float* xs   = (const float*)d_in[1];
  const int*   x1   = (const int*)d_in[2];
  const int*   su   = (const int*)d_in[3];
  const int*   ds   = (const int*)d_in[4];
  const int*   ss   = (const int*)d_in[5];
  const int*   du   = (const int*)d_in[6];
  const int*   mu   = (const int*)d_in[7];
  const int*   ms   = (const int*)d_in[8];
  const float* age  = (const float*)d_in[9];
  const float* gen  = (const float*)d_in[10];
  const float* W1ul = (const float*)d_in[11];
  const float* W1ur = (const float*)d_in[12];
  const float* b1u  = (const float*)d_in[13];
  const float* W1sl = (const float*)d_in[14];
  const float* W1sr = (const float*)d_in[15];
  const float* b1s  = (const float*)d_in[16];
  const float* W2ul = (const float*)d_in[17];
  const float* W2ur = (const float*)d_in[18];
  const float* b2u  = (const float*)d_in[19];
  const float* W2sl = (const float*)d_in[20];
  const float* W2sr = (const float*)d_in[21];
  const float* b2s  = (const float*)d_in[22];
  const float* lw   = (const float*)d_in[23];
  const float* lb   = (const float*)d_in[24];

  char* w = (char*)d_ws;
  ushort_t* aggU = (ushort_t*)(w + OFF_AGGU);
  ushort_t* aggS = (ushort_t*)(w + OFF_AGGS);
  ushort_t* ub   = (ushort_t*)(w + OFF_U);
  ushort_t* sb   = (ushort_t*)(w + OFF_S);
  ushort_t* xu16 = (ushort_t*)(w + OFF_XU16);
  ushort_t* xs16 = (ushort_t*)(w + OFF_XS16);
  float* tbl27   = (float*)(w + OFF_TBL27);
  ushort_t* z1u  = (ushort_t*)(w + OFF_Z1U);
  ushort_t* z1s  = (ushort_t*)(w + OFF_Z1S);
  ushort_t* z2u  = (ushort_t*)(w + OFF_Z2U);
  ushort_t* z2s  = (ushort_t*)(w + OFF_Z2S);
  int* rpU    = (int*)(w + OFF_RPU);
  int* rpS    = (int*)(w + OFF_RPS);
  int* csrU   = (int*)(w + OFF_CSRU);
  int* csrS   = (int*)(w + OFF_CSRS);
  int* histU  = (int*)(w + OFF_HIST);
  int* histS  = (int*)(w + OFF_HIST + 800000);
  int* curU   = (int*)(w + OFF_HIST + 1000000);
  int* curS   = (int*)(w + OFF_HIST + 1800000);
  int* hist12 = (int*)(w + OFF_HIST + 2000000);
  int* part   = (int*)(w + OFF_PART);
  float* out = (float*)d_out;

  // ---- CSR build (XCD-partitioned) + prep ----
  hipMemsetAsync(w + OFF_HIST, 0, 4400000, stream);  // histU|histS|curU|curS|hist12
  hist_k<<<8 * NSLICE, 256, 0, stream>>>(du, ds, histU, histS);
  scan1_k<<<NBU + NBS, 256, 0, stream>>>(histU, histS, rpU, rpS, part);
  scan2_k<<<2, 1024, 0, stream>>>(part);
  scan3_k<<<NBU + NBS, 256, 0, stream>>>(rpU, rpS, part);
  fill_k<<<8 * NSLICE, 256, 0, stream>>>(su, ds, ss, du, rpU, rpS, x1,
                                         curU, curS, csrU, csrS, hist12);
  prep_all_k<<<16031, 256, 0, stream>>>(xu, xs, x1, age, gen,
                                        W1ul, W1ur, W1sl, W1sr, W2ul, W2ur, W2sl, W2sr,
                                        xu16, xs16, ub, sb, tbl27, z1u, z1s, z2u, z2s);

  // ---- layer 1 ----
  gather1_k<<<(NU_N + NS_N) / 4, 256, 0, stream>>>(rpU, csrU, xs16, rpS, csrS, xu16,
                                                   hist12, aggU, aggS);
  gemm1_k<<<NUBG + NSBG, 256, 144 * 128 * 2, stream>>>(aggU, aggS, xu16, xs16, z1u, z1s,
                                                       b1u, b1s, tbl27, x1, ub, sb);

  // ---- layer 2 ----
  gather2_k<<<(NU_N + NS_N) / 4, 256, 0, stream>>>(rpU, csrU, sb, rpS, csrS, ub,
                                                   aggU, aggS);
  gemm2_k<<<NUBG + NSBG, 256, 256 * 128 * 2, stream>>>(aggU, aggS, z2u, z2s,
                                                       b2u, b2s, ub, sb);

  // ---- final linear + sigmoid ----
  final_k<<<(M_N * 64 + 255) / 256, 256, 0, stream>>>(ub, sb, mu, ms, lw, lb, out);
}